// Round 1
// 1317.881 us; speedup vs baseline: 2.5498x; 2.5498x over previous
//
#include <hip/hip_runtime.h>

#define NB 2
#define NS 4096
#define NH 16
#define NKV 8
#define ND 128
#define NM 256
#define NCNK 32

#define SCALE_A 0.29730177875068026f   // 128^-0.25
#define PHI_SCALE 0.0625f              // 256^-0.5
#define EPSF 1e-6f

typedef unsigned short u16;
typedef unsigned int u32;
typedef unsigned char u8;
typedef __attribute__((ext_vector_type(8))) short short8;
typedef __attribute__((ext_vector_type(4))) float f32x4;

// ---- bf16 <-> fp32 helpers --------------------------------------------------
static __device__ __forceinline__ float bfh(u16 v) {
  return __uint_as_float(((u32)v) << 16);
}
static __device__ __forceinline__ u32 f2bf1(float f) {
  u32 u = __float_as_uint(f);
  return (u + 0x7fffu + ((u >> 16) & 1u)) >> 16;
}
static __device__ __forceinline__ u32 pack2(float a, float b) {
  return f2bf1(a) | (f2bf1(b) << 16);
}
static __device__ __forceinline__ void unp8(uint4 p, float* f) {
  f[0] = __uint_as_float(p.x << 16); f[1] = __uint_as_float(p.x & 0xffff0000u);
  f[2] = __uint_as_float(p.y << 16); f[3] = __uint_as_float(p.y & 0xffff0000u);
  f[4] = __uint_as_float(p.z << 16); f[5] = __uint_as_float(p.z & 0xffff0000u);
  f[6] = __uint_as_float(p.w << 16); f[7] = __uint_as_float(p.w & 0xffff0000u);
}
static __device__ __forceinline__ void ld8(const u16* p, float* f) {
  unp8(*(const uint4*)p, f);
}
static __device__ __forceinline__ void ld8(const float* p, float* f) {
  const float4 a = *(const float4*)p;
  const float4 b = *(const float4*)(p + 4);
  f[0]=a.x; f[1]=a.y; f[2]=a.z; f[3]=a.w;
  f[4]=b.x; f[5]=b.y; f[6]=b.z; f[7]=b.w;
}
static __device__ __forceinline__ void st8(u16* p, const float* o) {
  uint4 w;
  w.x = pack2(o[0], o[1]); w.y = pack2(o[2], o[3]);
  w.z = pack2(o[4], o[5]); w.w = pack2(o[6], o[7]);
  *(uint4*)p = w;
}
static __device__ __forceinline__ void st8(float* p, const float* o) {
  *(float4*)(p + 0) = make_float4(o[0], o[1], o[2], o[3]);
  *(float4*)(p + 4) = make_float4(o[4], o[5], o[6], o[7]);
}

static __device__ __forceinline__ unsigned f2key(float f) {
  unsigned u = __float_as_uint(f);
  return (u & 0x80000000u) ? ~u : (u | 0x80000000u);
}
static __device__ __forceinline__ float key2f(unsigned k) {
  return (k & 0x80000000u) ? __uint_as_float(k & 0x7fffffffu) : __uint_as_float(~k);
}

__global__ void fill_out_f32(float* __restrict__ out, float val)
{
  const size_t idx = (size_t)blockIdx.x * 256 + threadIdx.x;
  out[idx] = val;
}

// ---------------------------------------------------------------------------
// f32 -> bf16 cast, 8 elems/thread, vectorized.
// ---------------------------------------------------------------------------
__global__ void f2b(const float* __restrict__ in, u16* __restrict__ out)
{
  const size_t i = (((size_t)blockIdx.x * 256) + threadIdx.x) * 8;
  float f[8];
  ld8(in + i, f);
  st8(out + i, f);
}

// ---------------------------------------------------------------------------
// MFMA NT GEMM (m97 structure): C[M,Nc] = A[M,K] @ B[Nc,K]^T, bf16 in, fp32
// accumulate, TO out. 128x128 tile / BK=32 / 256 threads (2x2 waves, each
// 64x64 via 4x4 of 16x16x32 MFMA). global_load_lds width-16 staging,
// single LDS buffer, 2 barriers per K-step. XCD-bijective block swizzle.
// Requires: M%128==0, Nc%128==0, K%32==0, 16B-aligned pointers.
// ---------------------------------------------------------------------------
#define GLL(gp, lp) \
  __builtin_amdgcn_global_load_lds( \
      (const __attribute__((address_space(1))) u32*)(gp), \
      (__attribute__((address_space(3))) u32*)(lp), 16, 0, 0)

static __device__ __forceinline__ void stc(float* p, float v) { *p = v; }
static __device__ __forceinline__ void stc(u16* p, float v)  { *p = (u16)f2bf1(v); }

template <class TO>
__global__ __launch_bounds__(256) void gemm_bt_mfma(
    const u16* __restrict__ A, const u16* __restrict__ B,
    TO* __restrict__ C, int K, int Nc)
{
  __shared__ u16 As[4096];   // [128 rows][32 k] bf16
  __shared__ u16 Bs[4096];
  const int t = threadIdx.x;
  const int lane = t & 63;
  const int wid = t >> 6;
  const int wr = wid >> 1, wc = wid & 1;

  // XCD-aware bijective swizzle (m204 formula; safe for any nwg)
  int bid = blockIdx.y * gridDim.x + blockIdx.x;
  {
    const int nwg = gridDim.x * gridDim.y;
    const int qq = nwg >> 3, rr = nwg & 7;
    const int x = bid & 7, o = bid >> 3;
    bid = (x < rr ? x * (qq + 1) : rr * (qq + 1) + (x - rr) * qq) + o;
  }
  const int rowBase = (bid / gridDim.x) * 128;
  const int colBase = (bid % gridDim.x) * 128;

  // staging: thread t covers LDS elems [t*8, t*8+8) (round 0) and +2048 (round 1)
  const int e0 = t * 8;                     // LDS element offset
  const int sk = (t & 3) * 8;               // k offset within BK=32
  const size_t g0 = (size_t)(rowBase + (t >> 2)) * K + sk;
  const size_t g1 = (size_t)(colBase + (t >> 2)) * K + sk;
  const size_t rstep = (size_t)K * 64;      // +64 rows for round 1

  // fragment read bases: row = fr (within 16), k = fk
  const int fr = lane & 15;
  const int fk = (lane >> 4) * 8;
  const u16* Ar = As + (wr * 64 + fr) * 32 + fk;
  const u16* Br = Bs + (wc * 64 + fr) * 32 + fk;

  f32x4 acc[4][4];
#pragma unroll
  for (int i = 0; i < 4; ++i)
#pragma unroll
    for (int j = 0; j < 4; ++j) acc[i][j] = (f32x4){0.f, 0.f, 0.f, 0.f};

  for (int k0 = 0; k0 < K; k0 += 32) {
    GLL(A + g0 + k0,         As + e0);
    GLL(A + g0 + rstep + k0, As + 2048 + e0);
    GLL(B + g1 + k0,         Bs + e0);
    GLL(B + g1 + rstep + k0, Bs + 2048 + e0);
    asm volatile("s_waitcnt vmcnt(0)" ::: "memory");
    __syncthreads();
    short8 a[4], b[4];
#pragma unroll
    for (int mi = 0; mi < 4; ++mi) a[mi] = *(const short8*)(Ar + mi * 512);
#pragma unroll
    for (int ni = 0; ni < 4; ++ni) b[ni] = *(const short8*)(Br + ni * 512);
#pragma unroll
    for (int mi = 0; mi < 4; ++mi)
#pragma unroll
      for (int ni = 0; ni < 4; ++ni)
        acc[mi][ni] = __builtin_amdgcn_mfma_f32_16x16x32_bf16(
            a[mi], b[ni], acc[mi][ni], 0, 0, 0);
    __syncthreads();
  }

  // C/D layout: col = lane&15, row = (lane>>4)*4 + reg (m89-verified)
  const int cr = (lane >> 4) * 4;
  const int cc = lane & 15;
#pragma unroll
  for (int mi = 0; mi < 4; ++mi) {
    const int r0 = rowBase + wr * 64 + mi * 16 + cr;
#pragma unroll
    for (int ni = 0; ni < 4; ++ni) {
      const int col = colBase + wc * 64 + ni * 16 + cc;
#pragma unroll
      for (int j = 0; j < 4; ++j)
        stc(C + (size_t)(r0 + j) * Nc + col, acc[mi][ni][j]);
    }
  }
}

// ---------------------------------------------------------------------------
// RoPE in place on bf16 x (B*S, nheads, D); cos/sin fp32 (B,S,D).
// ---------------------------------------------------------------------------
__global__ void rope_bf(u16* __restrict__ x, const float* __restrict__ cosb,
                        const float* __restrict__ sinb, int nheads)
{
  const size_t idx = (size_t)blockIdx.x * blockDim.x + threadIdx.x;
  const int d = (int)(idx & 63);
  const size_t nh = idx >> 6;
  const int h = (int)(nh % nheads);
  const size_t n = nh / nheads;
  const float c1 = cosb[n * ND + d];
  const float s1 = sinb[n * ND + d];
  const float c2 = cosb[n * ND + d + 64];
  const float s2 = sinb[n * ND + d + 64];
  u16* p = x + (n * (size_t)nheads + h) * ND + d;
  const float x1 = bfh(p[0]);
  const float x2 = bfh(p[64]);
  p[0]  = (u16)f2bf1(x1 * c1 - x2 * s1);
  p[64] = (u16)f2bf1(x2 * c2 + x1 * s2);
}

// ---------------------------------------------------------------------------
// Fused feature-map GEMM: U = feature(SCALE_A*X @ P^T), 128 rows/block.
// ---------------------------------------------------------------------------
template <bool IS_Q>
__global__ __launch_bounds__(256) void feat_gemm(
    const u16* __restrict__ X, const float* __restrict__ P,
    u16* __restrict__ U, unsigned* __restrict__ gmax)
{
  __shared__ float At[16][132];
  __shared__ float Bt[16][260];
  __shared__ float red[128][17];
  __shared__ float rowv[128];
  __shared__ float tmp[256];
  const int t  = threadIdx.x;
  const int tx = t & 15, ty = t >> 4;
  const int rowBase = blockIdx.x * 128;
  const int lr = t >> 1;
  const int lk = (t & 1) * 8;

  float acc[8][16];
#pragma unroll
  for (int i = 0; i < 8; ++i)
#pragma unroll
    for (int j = 0; j < 16; ++j) acc[i][j] = 0.f;
  float sqp = 0.f;

  for (int k0 = 0; k0 < 128; k0 += 16) {
    float af[8], bf0[8], bf1[8];
    ld8(X + (size_t)(rowBase + lr) * 128 + k0 + lk, af);
    ld8(P + (size_t)t * 128 + k0, bf0);
    ld8(P + (size_t)t * 128 + k0 + 8, bf1);
    __syncthreads();
#pragma unroll
    for (int j = 0; j < 8; ++j) {
      const float xs = af[j] * SCALE_A;
      At[lk+j][lr] = xs;
      sqp += xs * xs;
      Bt[j][t]   = bf0[j];
      Bt[8+j][t] = bf1[j];
    }
    __syncthreads();
#pragma unroll
    for (int kk = 0; kk < 16; ++kk) {
      float av[8], bv[16];
      *(float4*)&av[0]  = *(const float4*)&At[kk][ty*8];
      *(float4*)&av[4]  = *(const float4*)&At[kk][ty*8+4];
      *(float4*)&bv[0]  = *(const float4*)&Bt[kk][tx*16];
      *(float4*)&bv[4]  = *(const float4*)&Bt[kk][tx*16+4];
      *(float4*)&bv[8]  = *(const float4*)&Bt[kk][tx*16+8];
      *(float4*)&bv[12] = *(const float4*)&Bt[kk][tx*16+12];
#pragma unroll
      for (int i = 0; i < 8; ++i)
#pragma unroll
        for (int j = 0; j < 16; ++j) acc[i][j] += av[i]*bv[j];
    }
  }

  if (IS_Q) {
#pragma unroll
    for (int i = 0; i < 8; ++i) {
      float rp = -1e30f;
#pragma unroll
      for (int j = 0; j < 16; ++j) rp = fmaxf(rp, acc[i][j]);
      red[ty*8+i][tx] = rp;
    }
    __syncthreads();
    if (t < 128) {
      float mr = red[t][0];
#pragma unroll
      for (int x = 1; x < 16; ++x) mr = fmaxf(mr, red[t][x]);
      rowv[t] = mr;
    }
    __syncthreads();
#pragma unroll
    for (int i = 0; i < 8; ++i) {
      const float mr = rowv[ty*8+i];
      u16* up = U + (size_t)(rowBase + ty*8 + i) * NM + tx*16;
      float o[16];
#pragma unroll
      for (int j = 0; j < 16; ++j) o[j] = expf(acc[i][j] - mr) * PHI_SCALE + EPSF;
      st8(up, o);
      st8(up + 8, o + 8);
    }
  } else {
    tmp[t] = sqp;
    __syncthreads();
    if (t < 128) rowv[t] = 0.5f * (tmp[2*t] + tmp[2*t+1]);
    __syncthreads();
    float lmax = -1e30f;
#pragma unroll
    for (int i = 0; i < 8; ++i) {
      const float sq = rowv[ty*8+i];
#pragma unroll
      for (int j = 0; j < 16; ++j) {
        acc[i][j] -= sq;
        lmax = fmaxf(lmax, acc[i][j]);
      }
    }
    __syncthreads();
    tmp[t] = lmax;
    __syncthreads();
#pragma unroll
    for (int s2 = 128; s2 > 0; s2 >>= 1) {
      if (t < s2) tmp[t] = fmaxf(tmp[t], tmp[t + s2]);
      __syncthreads();
    }
    if (t == 0) atomicMax(gmax, f2key(tmp[0]));
#pragma unroll
    for (int i = 0; i < 8; ++i) {
      u16* up = U + (size_t)(rowBase + ty*8 + i) * NM + tx*16;
      float o[16];
#pragma unroll
      for (int j = 0; j < 16; ++j) o[j] = expf(acc[i][j]);
      st8(up, o);
      st8(up + 8, o + 8);
    }
  }
}

__global__ void init_gmax(unsigned* g) { *g = 0u; }

__global__ void feat_k_b(u16* __restrict__ u, const unsigned* __restrict__ gmax)
{
  const size_t idx = (size_t)blockIdx.x * blockDim.x + threadIdx.x;
  const float eg = expf(-key2f(*gmax));
  const float e = bfh(u[idx]);
  u[idx] = (u16)f2bf1(e * eg * PHI_SCALE + EPSF);
}

// ---------------------------------------------------------------------------
// Per-chunk KV state (bf16 out): KV[bkv][c][m][d], k_sum[bkv][c][m] (fp32).
// ---------------------------------------------------------------------------
__global__ __launch_bounds__(256) void chunk_kv(const u16* __restrict__ phik,
    const u16* __restrict__ v, u16* __restrict__ kvst, float* __restrict__ ksst)
{
  const int dg  = blockIdx.x;     // 0..7
  const int c   = blockIdx.y;     // 0..31
  const int bkv = blockIdx.z;     // b*NKV + kh
  const int b = bkv >> 3, kh = bkv & 7;
  const int t = threadIdx.x;
  __shared__ float Vt[128][20];
  {
    const int i = t >> 1;
    const int dseg = (t & 1) * 8;
    const u16* vp = v + ((size_t)(b*NS + c*128 + i) * NKV + kh) * ND + dg*16 + dseg;
    float vf[8];
    unp8(*(const uint4*)vp, vf);
#pragma unroll
    for (int j = 0; j < 8; ++j) Vt[i][dseg + j] = vf[j];
  }
  __syncthreads();
  const int m = t;
  const size_t pbase = ((size_t)(b*NS + c*128) * NKV + kh) * NM + m;
  const size_t pstr = (size_t)NKV * NM;
  float acc[16];
#pragma unroll
  for (int dl = 0; dl < 16; ++dl) acc[dl] = 0.f;
  float ks = 0.f;
  for (int i = 0; i < 128; ++i) {
    const float pk = bfh(phik[pbase + (size_t)i * pstr]);
    ks += pk;
#pragma unroll
    for (int dl = 0; dl < 16; ++dl) acc[dl] += pk * Vt[i][dl];
  }
  u16* op = kvst + (((size_t)bkv * NCNK + c) * NM + m) * ND + dg*16;
  st8(op, acc);
  st8(op + 8, acc + 8);
  if (dg == 0) ksst[((size_t)bkv * NCNK + c) * NM + m] = ks;
}

// Exclusive prefix over the 32 chunks (in place, bf16 storage, fp32 carry).
__global__ void prefix_kv(u16* __restrict__ kvst)
{
  const int md = blockIdx.x * 256 + threadIdx.x;        // 0..32767
  const size_t base = (size_t)blockIdx.y * NCNK * (NM*ND) + md;
  float carry = 0.f;
  for (int c = 0; c < NCNK; ++c) {
    const size_t a = base + (size_t)c * (NM*ND);
    const float val = bfh(kvst[a]);
    kvst[a] = (u16)f2bf1(carry);
    carry += val;
  }
}

__global__ void prefix_ks(float* __restrict__ ksst)
{
  const int m = threadIdx.x;
  const size_t base = (size_t)blockIdx.x * NCNK * NM + m;
  float carry = 0.f;
  for (int c = 0; c < NCNK; ++c) {
    const size_t a = base + (size_t)c * NM;
    const float val = ksst[a];
    ksst[a] = carry;
    carry += val;
  }
}

// ---------------------------------------------------------------------------
// Per-chunk attention, bf16 in / bf16 out (attn buffer), fp32 math.
// ---------------------------------------------------------------------------
__global__ __launch_bounds__(256) void attn_chunk(
    const u16* __restrict__ phiq, const u16* __restrict__ phik,
    const u16* __restrict__ v, const u16* __restrict__ kvpre,
    const float* __restrict__ kspre, u16* __restrict__ attn)
{
  const int c = blockIdx.x, h = blockIdx.y, b = blockIdx.z;
  const int kh = h >> 1;                 // groups = H/HKV = 2
  const int bkv = b * NKV + kh;
  const int t = threadIdx.x;
  const int tx = t & 15, ty = t >> 4;

  __shared__ float smem[8448];
  __shared__ float rsum[128][17];
  __shared__ float den_l[128];
  __shared__ float s_l[32];

  float (*Pq)[132]  = (float (*)[132])smem;
  float (*Pk)[132]  = (float (*)[132])(smem + 4224);
  float (*Asub)[33] = (float (*)[33])smem;
  float (*Vt2)[132] = (float (*)[132])(smem + 4224);
  float (*St)[132]  = (float (*)[132])(smem + 4224);

  const u16* pqc = phiq + ((size_t)(b*NS + c*128) * NH  + h)  * NM;
  const u16* pkc = phik + ((size_t)(b*NS + c*128) * NKV + kh) * NM;
  const size_t qstr = (size_t)NH * NM;
  const size_t kstr = (size_t)NKV * NM;

  const int lr = t >> 1;
  const int lm = (t & 1) * 16;

  float accA[8][8];
#pragma unroll
  for (int i = 0; i < 8; ++i)
#pragma unroll
    for (int j = 0; j < 8; ++j) accA[i][j] = 0.f;

  // ---- phase A: accA = Pq @ Pk^T
  for (int mt = 0; mt < 8; ++mt) {
    const int m0 = mt * 32;
    const u16* qp = pqc + (size_t)lr * qstr + m0 + lm;
    const u16* kp = pkc + (size_t)lr * kstr + m0 + lm;
    float qf[16], kf[16];
    unp8(*(const uint4*)qp, qf);     unp8(*(const uint4*)(qp+8), qf+8);
    unp8(*(const uint4*)kp, kf);     unp8(*(const uint4*)(kp+8), kf+8);
    __syncthreads();
#pragma unroll
    for (int j = 0; j < 16; ++j) { Pq[lm+j][lr] = qf[j]; Pk[lm+j][lr] = kf[j]; }
    __syncthreads();
    for (int mm = 0; mm < 32; ++mm) {
      float a[8], bb[8];
      *(float4*)&a[0]  = *(const float4*)&Pq[mm][ty*8];
      *(float4*)&a[4]  = *(const float4*)&Pq[mm][ty*8+4];
      *(float4*)&bb[0] = *(const float4*)&Pk[mm][tx*8];
      *(float4*)&bb[4] = *(const float4*)&Pk[mm][tx*8+4];
#pragma unroll
      for (int i = 0; i < 8; ++i)
#pragma unroll
        for (int j = 0; j < 8; ++j) accA[i][j] += a[i]*bb[j];
    }
  }

  // ---- phase B: causal mask + row-sum
#pragma unroll
  for (int ii = 0; ii < 8; ++ii) {
    const int i = ty*8 + ii;
    float rp = 0.f;
#pragma unroll
    for (int jj = 0; jj < 8; ++jj) {
      const int j = tx*8 + jj;
      if (j > i) accA[ii][jj] = 0.f;
      rp += accA[ii][jj];
    }
    rsum[i][tx] = rp;
  }
  __syncthreads();
  if (t < 128) {
    float s = 0.f;
#pragma unroll
    for (int x = 0; x < 16; ++x) s += rsum[t][x];
    den_l[t] = s;
  }

  float acc2[8][8];
#pragma unroll
  for (int i = 0; i < 8; ++i)
#pragma unroll
    for (int j = 0; j < 8; ++j) acc2[i][j] = 0.f;

  // ---- phase C: acc2 += A_masked @ V_chunk
  for (int jb = 0; jb < 4; ++jb) {
    __syncthreads();
    if ((tx >> 2) == jb) {
      const int jloc = (tx & 3) * 8;
#pragma unroll
      for (int ii = 0; ii < 8; ++ii)
#pragma unroll
        for (int jj = 0; jj < 8; ++jj)
          Asub[ty*8+ii][jloc+jj] = accA[ii][jj];
    }
    {
      const int jr = t >> 3;
      const int d0 = (t & 7) * 16;
      const u16* vp = v + ((size_t)(b*NS + c*128 + jb*32 + jr) * NKV + kh) * ND + d0;
      float vf[16];
      unp8(*(const uint4*)vp, vf);   unp8(*(const uint4*)(vp+8), vf+8);
#pragma unroll
      for (int j = 0; j < 16; ++j) Vt2[jr][d0 + j] = vf[j];
    }
    __syncthreads();
    for (int j2 = 0; j2 < 32; ++j2) {
      float a[8], bb[8];
#pragma unroll
      for (int ii = 0; ii < 8; ++ii) a[ii] = Asub[ty*8+ii][j2];
      *(float4*)&bb[0] = *(const float4*)&Vt2[j2][tx*8];
      *(float4*)&bb[4] = *(const float4*)&Vt2[j2][tx*8+4];
#pragma unroll
      for (int ii = 0; ii < 8; ++ii)
#pragma unroll
        for (int jj = 0; jj < 8; ++jj) acc2[ii][jj] += a[ii]*bb[jj];
    }
  }

  // ---- phase D: acc2 += Pq @ S_prefix ; pden = Pq @ s_prefix
  float pden[8];
#pragma unroll
  for (int ii = 0; ii < 8; ++ii) pden[ii] = 0.f;
  for (int mt = 0; mt < 8; ++mt) {
    const int m0 = mt * 32;
    const u16* qp = pqc + (size_t)lr * qstr + m0 + lm;
    float qf[16];
    unp8(*(const uint4*)qp, qf);   unp8(*(const uint4*)(qp+8), qf+8);
    const int mr = t >> 3;
    const int d0 = (t & 7) * 16;
    const u16* sp = kvpre + (((size_t)bkv * NCNK + c) * NM + m0 + mr) * ND + d0;
    float sf[16];
    unp8(*(const uint4*)sp, sf);   unp8(*(const uint4*)(sp+8), sf+8);
    __syncthreads();
#pragma unroll
    for (int j = 0; j < 16; ++j) Pq[lm+j][lr] = qf[j];
#pragma unroll
    for (int j = 0; j < 16; ++j) St[mr][d0 + j] = sf[j];
    if (t < 32) s_l[t] = kspre[((size_t)bkv * NCNK + c) * NM + m0 + t];
    __syncthreads();
    for (int mm = 0; mm < 32; ++mm) {
      float a[8], bb[8];
      *(float4*)&a[0]  = *(const float4*)&Pq[mm][ty*8];
      *(float4*)&a[4]  = *(const float4*)&Pq[mm][ty*8+4];
      *(float4*)&bb[0] = *(const float4*)&St[mm][tx*8];
      *(float4*)&bb[4] = *(const float4*)&St[mm][tx*8+4];
      const float sv = s_l[mm];
#pragma unroll
      for (int ii = 0; ii < 8; ++ii) {
        pden[ii] += a[ii] * sv;
#pragma unroll
        for (int jj = 0; jj < 8; ++jj) acc2[ii][jj] += a[ii]*bb[jj];
      }
    }
  }
  __syncthreads();
  if (tx == 0) {
#pragma unroll
    for (int ii = 0; ii < 8; ++ii) den_l[ty*8+ii] += pden[ii];
  }
  __syncthreads();

  // ---- output bf16 (intermediate attn buffer): num/(den+eps)
#pragma unroll
  for (int ii = 0; ii < 8; ++ii) {
    const int i = ty*8 + ii;
    const float inv = 1.0f / (den_l[i] + EPSF);
    u16* op = attn + ((size_t)(b*NS + c*128 + i) * NH + h) * ND + tx*8;
    float o[8];
#pragma unroll
    for (int jj = 0; jj < 8; ++jj) o[jj] = acc2[ii][jj] * inv;
    st8(op, o);
  }
}

// ---------------------------------------------------------------------------
extern "C" void kernel_launch(void* const* d_in, const int* in_sizes, int n_in,
                              void* d_out, int out_size, void* d_ws, size_t ws_size,
                              hipStream_t stream)
{
  const float* hidden = (const float*)d_in[0];
  const float* cosb   = (const float*)d_in[1];
  const float* sinb   = (const float*)d_in[2];
  const float* wq     = (const float*)d_in[3];
  const float* wk     = (const float*)d_in[4];
  const float* wv     = (const float*)d_in[5];
  const float* wo     = (const float*)d_in[6];
  const float* proj   = (const float*)d_in[7];
  float* out = (float*)d_out;

  const size_t MiB = 1024ull * 1024ull;
  if (ws_size < 180ull * MiB) {         // need 168.5 MiB; certified >=192 MiB
    fill_out_f32<<<65536, 256, 0, stream>>>(out, 400.f);
    return;
  }

  // workspace (~168.5 MiB):
  //   q(32M) | kv(16M) | phiq(64M) | kvst(32M, aliased as hb pre-chunk_kv)
  //   | ksst(0.5M) | gmax | wqb(8M) | wkb(4M) | wvb(4M) | wob(8M)
  u16* q    = (u16*)d_ws;                 // 16777216 bf16 (reused as attn)
  u16* kv   = q    + 16777216;            //  8388608 bf16 (k, then v)
  u16* phiq = kv   +  8388608;            // 33554432 bf16
  u16* kvst = phiq + 33554432;            // 16777216 bf16
  float* ksst = (float*)(kvst + 16777216);//   131072 f32
  unsigned* gmax = (unsigned*)(ksst + 131072);
  u16* wqb  = (u16*)(gmax + 64);          //  4194304 bf16
  u16* wkb  = wqb + 4194304;              //  2097152 bf16
  u16* wvb  = wkb + 2097152;              //  2097152 bf16
  u16* wob  = wvb + 2097152;              //  4194304 bf16
  u16* hb   = kvst;                       // 16777216 bf16 hidden; dead before chunk_kv
  u16* phik = (u16*)d_out;                // 16777216 bf16 in d_out's 64 MB;
                                          // dead before final GEMM overwrites
  u16* attn = q;

  // 0) fp32 -> bf16 casts (hidden + weights)
  f2b<<<8192, 256, 0, stream>>>(hidden, hb);
  f2b<<<2048, 256, 0, stream>>>(wq, wqb);
  f2b<<<1024, 256, 0, stream>>>(wk, wkb);
  f2b<<<1024, 256, 0, stream>>>(wv, wvb);
  f2b<<<2048, 256, 0, stream>>>(wo, wob);

  // 1) q,k projections (bf16 MFMA, fp32 accumulate -> bf16)
  gemm_bt_mfma<u16><<<dim3(16, 64), 256, 0, stream>>>(hb, wqb, q, 2048, 2048);
  gemm_bt_mfma<u16><<<dim3( 8, 64), 256, 0, stream>>>(hb, wkb, kv, 2048, 1024);

  // 2) RoPE in place
  rope_bf<<<32768, 256, 0, stream>>>(q, cosb, sinb, NH);
  rope_bf<<<16384, 256, 0, stream>>>(kv, cosb, sinb, NKV);

  // 3) fused feature-map GEMMs (k first: kv region is reused for v afterwards)
  init_gmax<<<1, 1, 0, stream>>>(gmax);
  feat_gemm<true ><<<1024, 256, 0, stream>>>(q, proj, phiq, gmax);
  feat_gemm<false><<< 512, 256, 0, stream>>>(kv, proj, phik, gmax);
  feat_k_b<<<65536, 256, 0, stream>>>(phik, gmax);

  // 4) v projection into the (now dead) k region; hb still alive (kvst unwritten)
  gemm_bt_mfma<u16><<<dim3( 8, 64), 256, 0, stream>>>(hb, wvb, kv, 2048, 1024);

  // 5) chunk states + exclusive prefix over chunks (overwrites hb alias)
  chunk_kv<<<dim3(8, NCNK, NB*NKV), 256, 0, stream>>>(phik, kv, kvst, ksst);
  prefix_kv<<<dim3(128, NB*NKV), 256, 0, stream>>>(kvst);
  prefix_ks<<<NB*NKV, 256, 0, stream>>>(ksst);

  // 6) per-chunk causal linear attention (writes attn into q region)
  attn_chunk<<<dim3(NCNK, NH, NB), 256, 0, stream>>>(phiq, phik, kv, kvst, ksst, attn);

  // 7) output projection (bf16 attn x bf16 wo -> FP32 out; overwrites phik)
  gemm_bt_mfma<float><<<dim3(16, 64), 256, 0, stream>>>(attn, wob, out, 2048, 2048);
}

// Round 2
// 808.372 us; speedup vs baseline: 4.1569x; 1.6303x over previous
//
#include <hip/hip_runtime.h>

#define NB 2
#define NS 4096
#define NH 16
#define NKV 8
#define ND 128
#define NM 256
#define NCNK 32

#define SCALE_A 0.29730177875068026f   // 128^-0.25
#define PHI_SCALE 0.0625f              // 256^-0.5
#define EPSF 1e-6f

typedef unsigned short u16;
typedef unsigned int u32;
typedef __attribute__((ext_vector_type(8))) short short8;
typedef __attribute__((ext_vector_type(4))) float f32x4;

// ---- bf16 <-> fp32 helpers --------------------------------------------------
static __device__ __forceinline__ float bfh(u16 v) {
  return __uint_as_float(((u32)v) << 16);
}
static __device__ __forceinline__ u32 f2bf1(float f) {
  u32 u = __float_as_uint(f);
  return (u + 0x7fffu + ((u >> 16) & 1u)) >> 16;
}
static __device__ __forceinline__ u32 pack2(float a, float b) {
  return f2bf1(a) | (f2bf1(b) << 16);
}
static __device__ __forceinline__ void unp8(uint4 p, float* f) {
  f[0] = __uint_as_float(p.x << 16); f[1] = __uint_as_float(p.x & 0xffff0000u);
  f[2] = __uint_as_float(p.y << 16); f[3] = __uint_as_float(p.y & 0xffff0000u);
  f[4] = __uint_as_float(p.z << 16); f[5] = __uint_as_float(p.z & 0xffff0000u);
  f[6] = __uint_as_float(p.w << 16); f[7] = __uint_as_float(p.w & 0xffff0000u);
}
static __device__ __forceinline__ void ld8(const u16* p, float* f) {
  unp8(*(const uint4*)p, f);
}
static __device__ __forceinline__ void ld8(const float* p, float* f) {
  const float4 a = *(const float4*)p;
  const float4 b = *(const float4*)(p + 4);
  f[0]=a.x; f[1]=a.y; f[2]=a.z; f[3]=a.w;
  f[4]=b.x; f[5]=b.y; f[6]=b.z; f[7]=b.w;
}
static __device__ __forceinline__ void st8(u16* p, const float* o) {
  uint4 w;
  w.x = pack2(o[0], o[1]); w.y = pack2(o[2], o[3]);
  w.z = pack2(o[4], o[5]); w.w = pack2(o[6], o[7]);
  *(uint4*)p = w;
}

static __device__ __forceinline__ unsigned f2key(float f) {
  unsigned u = __float_as_uint(f);
  return (u & 0x80000000u) ? ~u : (u | 0x80000000u);
}
static __device__ __forceinline__ float key2f(unsigned k) {
  return (k & 0x80000000u) ? __uint_as_float(k & 0x7fffffffu) : __uint_as_float(~k);
}

__global__ void fill_out_f32(float* __restrict__ out, float val)
{
  const size_t idx = (size_t)blockIdx.x * 256 + threadIdx.x;
  out[idx] = val;
}

// ---------------------------------------------------------------------------
// f32 -> bf16 cast, 8 elems/thread.
// ---------------------------------------------------------------------------
__global__ void f2b(const float* __restrict__ in, u16* __restrict__ out)
{
  const size_t i = (((size_t)blockIdx.x * 256) + threadIdx.x) * 8;
  float f[8];
  ld8(in + i, f);
  st8(out + i, f);
}

// f32 -> bf16 hi/lo split (exact to ~1e-5 rel when recombined)
__global__ void f2b_split(const float* __restrict__ in, u16* __restrict__ hi,
                          u16* __restrict__ lo)
{
  const size_t i = (size_t)blockIdx.x * 256 + threadIdx.x;
  const float f = in[i];
  const u16 h = (u16)f2bf1(f);
  hi[i] = h;
  lo[i] = (u16)f2bf1(f - bfh(h));
}

// ---------------------------------------------------------------------------
// MFMA NT GEMM (m97 structure): C[M,Nc] = A[M,K] @ B[Nc,K]^T.
// ---------------------------------------------------------------------------
#define GLL(gp, lp) \
  __builtin_amdgcn_global_load_lds( \
      (const __attribute__((address_space(1))) u32*)(gp), \
      (__attribute__((address_space(3))) u32*)(lp), 16, 0, 0)

static __device__ __forceinline__ void stc(float* p, float v) { *p = v; }
static __device__ __forceinline__ void stc(u16* p, float v)  { *p = (u16)f2bf1(v); }

template <class TO>
__global__ __launch_bounds__(256) void gemm_bt_mfma(
    const u16* __restrict__ A, const u16* __restrict__ B,
    TO* __restrict__ C, int K, int Nc)
{
  __shared__ u16 As[4096];   // [128 rows][32 k] bf16
  __shared__ u16 Bs[4096];
  const int t = threadIdx.x;
  const int lane = t & 63;
  const int wid = t >> 6;
  const int wr = wid >> 1, wc = wid & 1;

  int bid = blockIdx.y * gridDim.x + blockIdx.x;
  {
    const int nwg = gridDim.x * gridDim.y;
    const int qq = nwg >> 3, rr = nwg & 7;
    const int x = bid & 7, o = bid >> 3;
    bid = (x < rr ? x * (qq + 1) : rr * (qq + 1) + (x - rr) * qq) + o;
  }
  const int rowBase = (bid / gridDim.x) * 128;
  const int colBase = (bid % gridDim.x) * 128;

  const int e0 = t * 8;
  const int sk = (t & 3) * 8;
  const size_t g0 = (size_t)(rowBase + (t >> 2)) * K + sk;
  const size_t g1 = (size_t)(colBase + (t >> 2)) * K + sk;
  const size_t rstep = (size_t)K * 64;

  const int fr = lane & 15;
  const int fk = (lane >> 4) * 8;
  const u16* Ar = As + (wr * 64 + fr) * 32 + fk;
  const u16* Br = Bs + (wc * 64 + fr) * 32 + fk;

  f32x4 acc[4][4];
#pragma unroll
  for (int i = 0; i < 4; ++i)
#pragma unroll
    for (int j = 0; j < 4; ++j) acc[i][j] = (f32x4){0.f, 0.f, 0.f, 0.f};

  for (int k0 = 0; k0 < K; k0 += 32) {
    GLL(A + g0 + k0,         As + e0);
    GLL(A + g0 + rstep + k0, As + 2048 + e0);
    GLL(B + g1 + k0,         Bs + e0);
    GLL(B + g1 + rstep + k0, Bs + 2048 + e0);
    asm volatile("s_waitcnt vmcnt(0)" ::: "memory");
    __syncthreads();
    short8 a[4], b[4];
#pragma unroll
    for (int mi = 0; mi < 4; ++mi) a[mi] = *(const short8*)(Ar + mi * 512);
#pragma unroll
    for (int ni = 0; ni < 4; ++ni) b[ni] = *(const short8*)(Br + ni * 512);
#pragma unroll
    for (int mi = 0; mi < 4; ++mi)
#pragma unroll
      for (int ni = 0; ni < 4; ++ni)
        acc[mi][ni] = __builtin_amdgcn_mfma_f32_16x16x32_bf16(
            a[mi], b[ni], acc[mi][ni], 0, 0, 0);
    __syncthreads();
  }

  const int cr = (lane >> 4) * 4;
  const int cc = lane & 15;
#pragma unroll
  for (int mi = 0; mi < 4; ++mi) {
    const int r0 = rowBase + wr * 64 + mi * 16 + cr;
#pragma unroll
    for (int ni = 0; ni < 4; ++ni) {
      const int col = colBase + wc * 64 + ni * 16 + cc;
#pragma unroll
      for (int j = 0; j < 4; ++j)
        stc(C + (size_t)(r0 + j) * Nc + col, acc[mi][ni][j]);
    }
  }
}

// ---------------------------------------------------------------------------
// RoPE in place on bf16 x (B*S, nheads, D); cos/sin fp32 (B,S,D).
// ---------------------------------------------------------------------------
__global__ void rope_bf(u16* __restrict__ x, const float* __restrict__ cosb,
                        const float* __restrict__ sinb, int nheads)
{
  const size_t idx = (size_t)blockIdx.x * blockDim.x + threadIdx.x;
  const int d = (int)(idx & 63);
  const size_t nh = idx >> 6;
  const int h = (int)(nh % nheads);
  const size_t n = nh / nheads;
  const float c1 = cosb[n * ND + d];
  const float s1 = sinb[n * ND + d];
  const float c2 = cosb[n * ND + d + 64];
  const float s2 = sinb[n * ND + d + 64];
  u16* p = x + (n * (size_t)nheads + h) * ND + d;
  const float x1 = bfh(p[0]);
  const float x2 = bfh(p[64]);
  p[0]  = (u16)f2bf1(x1 * c1 - x2 * s1);
  p[64] = (u16)f2bf1(x2 * c2 + x1 * s2);
}

// ---------------------------------------------------------------------------
// sq[row] = 0.5 * SCALE_A^2 * sum_d x[row][d]^2  (k rows)
// ---------------------------------------------------------------------------
__global__ void sqsum_k(const u16* __restrict__ X, float* __restrict__ sqv)
{
  const size_t row = (size_t)blockIdx.x * 256 + threadIdx.x;
  const u16* p = X + row * 128;
  float s = 0.f;
  for (int k = 0; k < 128; k += 8) {
    float f[8];
    ld8(p + k, f);
#pragma unroll
    for (int j = 0; j < 8; ++j) s += f[j] * f[j];
  }
  sqv[row] = 0.5f * SCALE_A * SCALE_A * s;
}

// ---------------------------------------------------------------------------
// MFMA feature-map GEMM: raw = X[128 rows][128] @ P^T (P split hi/lo bf16),
// tile 128x256 (full M), epilogue applies feature map.
// ---------------------------------------------------------------------------
template <bool IS_Q>
__global__ __launch_bounds__(256) void feat_mfma(
    const u16* __restrict__ X, const u16* __restrict__ Pb,
    u16* __restrict__ U, const float* __restrict__ sqv,
    unsigned* __restrict__ gmax)
{
  __shared__ u16 As[4096];   // [128][32]
  __shared__ u16 Bs[8192];   // [256][32]
  __shared__ float rmW[2][128];
  __shared__ float wmax[4];
  const int t = threadIdx.x;
  const int lane = t & 63, wid = t >> 6;
  const int wr = wid >> 1, wc = wid & 1;
  const int fr = lane & 15, fk = (lane >> 4) * 8;
  const int cr = (lane >> 4) * 4, cc = lane & 15;
  const int sr = t >> 2, sk = (t & 3) * 8, e0 = t * 8;
  const size_t rowBase = (size_t)blockIdx.x * 128;

  f32x4 acc[4][8];
#pragma unroll
  for (int i = 0; i < 4; ++i)
#pragma unroll
    for (int j = 0; j < 8; ++j) acc[i][j] = (f32x4){0.f, 0.f, 0.f, 0.f};

  for (int pp = 0; pp < 2; ++pp) {
    const u16* P2 = Pb + pp * (NM * 128);
    for (int k0 = 0; k0 < 128; k0 += 32) {
      GLL(X + (rowBase + sr) * 128 + k0 + sk,        As + e0);
      GLL(X + (rowBase + sr + 64) * 128 + k0 + sk,   As + 2048 + e0);
      GLL(P2 + (size_t)sr * 128 + k0 + sk,           Bs + e0);
      GLL(P2 + (size_t)(sr + 64) * 128 + k0 + sk,    Bs + 2048 + e0);
      GLL(P2 + (size_t)(sr + 128) * 128 + k0 + sk,   Bs + 4096 + e0);
      GLL(P2 + (size_t)(sr + 192) * 128 + k0 + sk,   Bs + 6144 + e0);
      asm volatile("s_waitcnt vmcnt(0)" ::: "memory");
      __syncthreads();
      short8 a[4], bb[8];
#pragma unroll
      for (int mi = 0; mi < 4; ++mi)
        a[mi] = *(const short8*)(As + (wr*64 + mi*16 + fr)*32 + fk);
#pragma unroll
      for (int ni = 0; ni < 8; ++ni)
        bb[ni] = *(const short8*)(Bs + (wc*128 + ni*16 + fr)*32 + fk);
#pragma unroll
      for (int mi = 0; mi < 4; ++mi)
#pragma unroll
        for (int ni = 0; ni < 8; ++ni)
          acc[mi][ni] = __builtin_amdgcn_mfma_f32_16x16x32_bf16(
              a[mi], bb[ni], acc[mi][ni], 0, 0, 0);
      __syncthreads();
    }
  }

  if (IS_Q) {
    // row max of raw over all 256 cols
#pragma unroll
    for (int mi = 0; mi < 4; ++mi)
#pragma unroll
      for (int j = 0; j < 4; ++j) {
        float m = acc[mi][0][j];
#pragma unroll
        for (int ni = 1; ni < 8; ++ni) m = fmaxf(m, acc[mi][ni][j]);
        m = fmaxf(m, __shfl_xor(m, 1));
        m = fmaxf(m, __shfl_xor(m, 2));
        m = fmaxf(m, __shfl_xor(m, 4));
        m = fmaxf(m, __shfl_xor(m, 8));
        const int r = wr*64 + mi*16 + cr + j;
        if (cc == 0) rmW[wc][r] = m;
      }
    __syncthreads();
#pragma unroll
    for (int mi = 0; mi < 4; ++mi)
#pragma unroll
      for (int j = 0; j < 4; ++j) {
        const int r = wr*64 + mi*16 + cr + j;
        const float mr = fmaxf(rmW[0][r], rmW[1][r]);
        u16* up = U + (rowBase + r) * NM + wc*128 + cc;
#pragma unroll
        for (int ni = 0; ni < 8; ++ni) {
          const float phi = expf(SCALE_A * (acc[mi][ni][j] - mr)) * PHI_SCALE + EPSF;
          up[ni*16] = (u16)f2bf1(phi);
        }
      }
  } else {
    float lmax = -1e30f;
#pragma unroll
    for (int mi = 0; mi < 4; ++mi)
#pragma unroll
      for (int j = 0; j < 4; ++j) {
        const int r = wr*64 + mi*16 + cr + j;
        const float sq = sqv[rowBase + r];
#pragma unroll
        for (int ni = 0; ni < 8; ++ni) {
          const float z = SCALE_A * acc[mi][ni][j] - sq;
          acc[mi][ni][j] = z;
          lmax = fmaxf(lmax, z);
        }
      }
    lmax = fmaxf(lmax, __shfl_xor(lmax, 1));
    lmax = fmaxf(lmax, __shfl_xor(lmax, 2));
    lmax = fmaxf(lmax, __shfl_xor(lmax, 4));
    lmax = fmaxf(lmax, __shfl_xor(lmax, 8));
    lmax = fmaxf(lmax, __shfl_xor(lmax, 16));
    lmax = fmaxf(lmax, __shfl_xor(lmax, 32));
    if (lane == 0) wmax[wid] = lmax;
    __syncthreads();
    if (t == 0) {
      const float bm = fmaxf(fmaxf(wmax[0], wmax[1]), fmaxf(wmax[2], wmax[3]));
      atomicMax(gmax, f2key(bm));
    }
#pragma unroll
    for (int mi = 0; mi < 4; ++mi)
#pragma unroll
      for (int j = 0; j < 4; ++j) {
        const int r = wr*64 + mi*16 + cr + j;
        u16* up = U + (rowBase + r) * NM + wc*128 + cc;
#pragma unroll
        for (int ni = 0; ni < 8; ++ni)
          up[ni*16] = (u16)f2bf1(expf(acc[mi][ni][j]));
      }
  }
}

__global__ void init_gmax(unsigned* g) { *g = 0u; }

__global__ void feat_k_b(u16* __restrict__ u, const unsigned* __restrict__ gmax)
{
  const size_t idx = (size_t)blockIdx.x * blockDim.x + threadIdx.x;
  const float eg = expf(-key2f(*gmax));
  const float e = bfh(u[idx]);
  u[idx] = (u16)f2bf1(e * eg * PHI_SCALE + EPSF);
}

// ---------------------------------------------------------------------------
// Per-chunk KV state, TRANSPOSED out: KV^T[bkv][c][d][m] bf16; k_sum fp32.
// Stores per dl are contiguous across threads (m = t) -> coalesced.
// ---------------------------------------------------------------------------
__global__ __launch_bounds__(256) void chunk_kv(const u16* __restrict__ phik,
    const u16* __restrict__ v, u16* __restrict__ kvT, float* __restrict__ ksst)
{
  const int dg  = blockIdx.x;     // 0..7
  const int c   = blockIdx.y;     // 0..31
  const int bkv = blockIdx.z;
  const int b = bkv >> 3, kh = bkv & 7;
  const int t = threadIdx.x;
  __shared__ float Vt[128][20];
  {
    const int i = t >> 1;
    const int dseg = (t & 1) * 8;
    const u16* vp = v + ((size_t)(b*NS + c*128 + i) * NKV + kh) * ND + dg*16 + dseg;
    float vf[8];
    unp8(*(const uint4*)vp, vf);
#pragma unroll
    for (int j = 0; j < 8; ++j) Vt[i][dseg + j] = vf[j];
  }
  __syncthreads();
  const int m = t;
  const size_t pbase = ((size_t)(b*NS + c*128) * NKV + kh) * NM + m;
  const size_t pstr = (size_t)NKV * NM;
  float acc[16];
#pragma unroll
  for (int dl = 0; dl < 16; ++dl) acc[dl] = 0.f;
  float ks = 0.f;
  for (int i = 0; i < 128; ++i) {
    const float pk = bfh(phik[pbase + (size_t)i * pstr]);
    ks += pk;
#pragma unroll
    for (int dl = 0; dl < 16; ++dl) acc[dl] += pk * Vt[i][dl];
  }
  const size_t ob = ((size_t)bkv * NCNK + c) * (ND*NM) + (size_t)(dg*16) * NM + m;
#pragma unroll
  for (int dl = 0; dl < 16; ++dl)
    kvT[ob + (size_t)dl * NM] = (u16)f2bf1(acc[dl]);
  if (dg == 0) ksst[((size_t)bkv * NCNK + c) * NM + m] = ks;
}

// Exclusive prefix over the 32 chunks (layout-agnostic elementwise walk).
__global__ void prefix_kv(u16* __restrict__ kvst)
{
  const int md = blockIdx.x * 256 + threadIdx.x;        // 0..32767
  const size_t base = (size_t)blockIdx.y * NCNK * (NM*ND) + md;
  float carry = 0.f;
  for (int c = 0; c < NCNK; ++c) {
    const size_t a = base + (size_t)c * (NM*ND);
    const float val = bfh(kvst[a]);
    kvst[a] = (u16)f2bf1(carry);
    carry += val;
  }
}

__global__ void prefix_ks(float* __restrict__ ksst)
{
  const int m = threadIdx.x;
  const size_t base = (size_t)blockIdx.x * NCNK * NM + m;
  float carry = 0.f;
  for (int c = 0; c < NCNK; ++c) {
    const size_t a = base + (size_t)c * NM;
    const float val = ksst[a];
    ksst[a] = carry;
    carry += val;
  }
}

// ---------------------------------------------------------------------------
// V transpose: v[b*NS+s][kh][d] -> vT[b][kh][d][s]   (64x64 LDS tiles)
// ---------------------------------------------------------------------------
__global__ __launch_bounds__(256) void vtrans(const u16* __restrict__ v,
                                              u16* __restrict__ vT)
{
  const int s0 = blockIdx.x * 64;
  const int d0 = blockIdx.y * 64;
  const int bkv = blockIdx.z;
  const int b = bkv >> 3, kh = bkv & 7;
  const int t = threadIdx.x;
  __shared__ u16 Tt[64][80];
  const int sl = t >> 3;          // 0..31
  const int ds = (t & 7) * 8;
#pragma unroll
  for (int r = 0; r < 2; ++r) {
    const u16* src = v + ((size_t)(b*NS + s0 + r*32 + sl) * NKV + kh) * ND + d0 + ds;
    *(uint4*)&Tt[r*32 + sl][ds] = *(const uint4*)src;
  }
  __syncthreads();
#pragma unroll
  for (int r = 0; r < 2; ++r) {
    const int dl = r*32 + sl;
    u16 tmp[8];
#pragma unroll
    for (int j = 0; j < 8; ++j) tmp[j] = Tt[ds + j][dl];
    u16* dst = vT + (((size_t)(b*NKV + kh) * ND) + d0 + dl) * NS + s0 + ds;
    *(uint4*)dst = *(uint4*)tmp;
  }
}

// ---------------------------------------------------------------------------
// MFMA per-chunk causal linear attention.
//   A: S = Pq @ Pk^T (K=256); mask + rowsum (shfl + LDS atomics); S->LDS bf16
//      with XOR swizzle (byte ^= (row&7)<<4).
//   C: acc2 += S @ V      (A-frags from swizzled LDS, B from vT rows)
//   D: acc2 += Pq @ KVpre (B from kvT rows); pden folded from staged Pq.
// ---------------------------------------------------------------------------
__global__ __launch_bounds__(256) void attn_mfma(
    const u16* __restrict__ phiq, const u16* __restrict__ phik,
    const u16* __restrict__ vT, const u16* __restrict__ kvT,
    const float* __restrict__ kspre, u16* __restrict__ attn)
{
  const int c = blockIdx.x, h = blockIdx.y, b = blockIdx.z;
  const int kh = h >> 1;                 // groups = 2
  const int bkv = b * NKV + kh;
  const int t = threadIdx.x;
  const int lane = t & 63, wid = t >> 6;
  const int wr = wid >> 1, wc = wid & 1;
  const int fr = lane & 15, fk = (lane >> 4) * 8;
  const int cr = (lane >> 4) * 4, cc = lane & 15;
  const int sr = t >> 2, sk = (t & 3) * 8, e0 = t * 8;

  __shared__ u16 As[4096];      // [128][32]
  __shared__ u16 Bs[4096];      // [128][32]
  __shared__ u16 Sl[16384];     // [128][128] swizzled bf16
  __shared__ float den_l[128];
  __shared__ float ks_l[256];

  const size_t pq_off = ((size_t)(b*NS + c*128) * NH  + h)  * NM;
  const size_t pk_off = ((size_t)(b*NS + c*128) * NKV + kh) * NM;
  const size_t vt_off = ((size_t)(b*NKV + kh) * ND) * (size_t)NS + (size_t)c * 128;
  const size_t kv_off = ((size_t)bkv * NCNK + c) * (size_t)(ND*NM);

  if (t < 128) den_l[t] = 0.f;
  ks_l[t] = kspre[((size_t)bkv * NCNK + c) * NM + t];

  const u16* Arp = As + (wr*64 + fr)*32 + fk;
  const u16* Brp = Bs + (wc*64 + fr)*32 + fk;

  // ---- phase A: S = Pq @ Pk^T -------------------------------------------
  f32x4 accS[4][4];
#pragma unroll
  for (int i = 0; i < 4; ++i)
#pragma unroll
    for (int j = 0; j < 4; ++j) accS[i][j] = (f32x4){0.f, 0.f, 0.f, 0.f};

  for (int k0 = 0; k0 < NM; k0 += 32) {
    GLL(phiq + pq_off + (size_t)sr * 4096 + k0 + sk,        As + e0);
    GLL(phiq + pq_off + (size_t)(sr + 64) * 4096 + k0 + sk, As + 2048 + e0);
    GLL(phik + pk_off + (size_t)sr * 2048 + k0 + sk,        Bs + e0);
    GLL(phik + pk_off + (size_t)(sr + 64) * 2048 + k0 + sk, Bs + 2048 + e0);
    asm volatile("s_waitcnt vmcnt(0)" ::: "memory");
    __syncthreads();
    short8 a[4], bb[4];
#pragma unroll
    for (int mi = 0; mi < 4; ++mi) a[mi] = *(const short8*)(Arp + mi*512);
#pragma unroll
    for (int ni = 0; ni < 4; ++ni) bb[ni] = *(const short8*)(Brp + ni*512);
#pragma unroll
    for (int mi = 0; mi < 4; ++mi)
#pragma unroll
      for (int ni = 0; ni < 4; ++ni)
        accS[mi][ni] = __builtin_amdgcn_mfma_f32_16x16x32_bf16(
            a[mi], bb[ni], accS[mi][ni], 0, 0, 0);
    __syncthreads();
  }

  // ---- mask + rowsum + write S to swizzled LDS ---------------------------
#pragma unroll
  for (int mi = 0; mi < 4; ++mi)
#pragma unroll
    for (int j = 0; j < 4; ++j) {
      const int r = wr*64 + mi*16 + cr + j;
      float s = 0.f;
#pragma unroll
      for (int ni = 0; ni < 4; ++ni) {
        const int cl = wc*64 + ni*16 + cc;
        float vv = accS[mi][ni][j];
        vv = (cl > r) ? 0.f : vv;
        accS[mi][ni][j] = vv;
        s += vv;
      }
      s += __shfl_xor(s, 1); s += __shfl_xor(s, 2);
      s += __shfl_xor(s, 4); s += __shfl_xor(s, 8);
      if (cc == 0) atomicAdd(&den_l[r], s);
#pragma unroll
      for (int ni = 0; ni < 4; ++ni) {
        const int cl = wc*64 + ni*16 + cc;
        u32 bo = ((u32)r << 8) + ((u32)cl << 1);
        bo ^= (u32)(r & 7) << 4;
        *(u16*)((char*)Sl + bo) = (u16)f2bf1(accS[mi][ni][j]);
      }
    }
  __syncthreads();

  // ---- phase C: acc2 = S @ V  (B-rows = vT[d][s]) ------------------------
  f32x4 acc2[4][4];
#pragma unroll
  for (int i = 0; i < 4; ++i)
#pragma unroll
    for (int j = 0; j < 4; ++j) acc2[i][j] = (f32x4){0.f, 0.f, 0.f, 0.f};

  for (int j0 = 0; j0 < 128; j0 += 32) {
    GLL(vT + vt_off + (size_t)sr * NS + j0 + sk,        Bs + e0);
    GLL(vT + vt_off + (size_t)(sr + 64) * NS + j0 + sk, Bs + 2048 + e0);
    asm volatile("s_waitcnt vmcnt(0)" ::: "memory");
    __syncthreads();
    short8 a[4], bb[4];
#pragma unroll
    for (int mi = 0; mi < 4; ++mi) {
      u32 bo = ((u32)(wr*64 + mi*16 + fr) << 8) + ((u32)(j0 + fk) << 1);
      bo ^= (u32)(fr & 7) << 4;
      a[mi] = *(const short8*)((const char*)Sl + bo);
    }
#pragma unroll
    for (int ni = 0; ni < 4; ++ni) bb[ni] = *(const short8*)(Brp + ni*512);
#pragma unroll
    for (int mi = 0; mi < 4; ++mi)
#pragma unroll
      for (int ni = 0; ni < 4; ++ni)
        acc2[mi][ni] = __builtin_amdgcn_mfma_f32_16x16x32_bf16(
            a[mi], bb[ni], acc2[mi][ni], 0, 0, 0);
    __syncthreads();
  }

  // ---- phase D: acc2 += Pq @ KVpre ; den += Pq . ks_prefix ---------------
  for (int m0 = 0; m0 < NM; m0 += 32) {
    GLL(phiq + pq_off + (size_t)sr * 4096 + m0 + sk,        As + e0);
    GLL(phiq + pq_off + (size_t)(sr + 64) * 4096 + m0 + sk, As + 2048 + e0);
    GLL(kvT + kv_off + (size_t)sr * NM + m0 + sk,           Bs + e0);
    GLL(kvT + kv_off + (size_t)(sr + 64) * NM + m0 + sk,    Bs + 2048 + e0);
    asm volatile("s_waitcnt vmcnt(0)" ::: "memory");
    __syncthreads();
    short8 a[4], bb[4];
#pragma unroll
    for (int mi = 0; mi < 4; ++mi) a[mi] = *(const short8*)(Arp + mi*512);
#pragma unroll
    for (int ni = 0; ni < 4; ++ni) bb[ni] = *(const short8*)(Brp + ni*512);
#pragma unroll
    for (int mi = 0; mi < 4; ++mi)
#pragma unroll
      for (int ni = 0; ni < 4; ++ni)
        acc2[mi][ni] = __builtin_amdgcn_mfma_f32_16x16x32_bf16(
            a[mi], bb[ni], acc2[mi][ni], 0, 0, 0);
    // pden partial from the staged Pq slice
    {
      const int pr = t >> 1;
      const int pm = (t & 1) * 16;
      float xf[16];
      unp8(*(const uint4*)(As + pr*32 + pm), xf);
      unp8(*(const uint4*)(As + pr*32 + pm + 8), xf + 8);
      float s = 0.f;
#pragma unroll
      for (int jj = 0; jj < 16; ++jj) s += xf[jj] * ks_l[m0 + pm + jj];
      s += __shfl_xor(s, 1);
      if (!(t & 1)) atomicAdd(&den_l[pr], s);
    }
    __syncthreads();
  }

  // ---- epilogue: out = acc2 / (den + eps) --------------------------------
#pragma unroll
  for (int mi = 0; mi < 4; ++mi)
#pragma unroll
    for (int j = 0; j < 4; ++j) {
      const int r = wr*64 + mi*16 + cr + j;
      const float inv = 1.0f / (den_l[r] + EPSF);
      u16* op = attn + ((size_t)(b*NS + c*128 + r) * NH + h) * ND + wc*64 + cc;
#pragma unroll
      for (int ni = 0; ni < 4; ++ni)
        op[ni*16] = (u16)f2bf1(acc2[mi][ni][j] * inv);
    }
}

// ---------------------------------------------------------------------------
extern "C" void kernel_launch(void* const* d_in, const int* in_sizes, int n_in,
                              void* d_out, int out_size, void* d_ws, size_t ws_size,
                              hipStream_t stream)
{
  const float* hidden = (const float*)d_in[0];
  const float* cosb   = (const float*)d_in[1];
  const float* sinb   = (const float*)d_in[2];
  const float* wq     = (const float*)d_in[3];
  const float* wk     = (const float*)d_in[4];
  const float* wv     = (const float*)d_in[5];
  const float* wo     = (const float*)d_in[6];
  const float* proj   = (const float*)d_in[7];
  float* out = (float*)d_out;

  const size_t MiB = 1024ull * 1024ull;
  if (ws_size < 180ull * MiB) {
    fill_out_f32<<<65536, 256, 0, stream>>>(out, 400.f);
    return;
  }

  // workspace (~169 MiB):
  u16* q    = (u16*)d_ws;                 // 16777216 bf16 (reused as attn)
  u16* kv   = q    + 16777216;            //  8388608 bf16 (k, then v)
  u16* phiq = kv   +  8388608;            // 33554432 bf16
  u16* kvst = phiq + 33554432;            // 16777216 bf16 (KV^T chunk states)
  float* ksst = (float*)(kvst + 16777216);//   131072 f32
  unsigned* gmax = (unsigned*)(ksst + 131072);
  float* sqv = (float*)(gmax + 64);       //    65536 f32
  u16* wqb  = (u16*)(sqv + 65536);        //  4194304 bf16
  u16* wkb  = wqb + 4194304;              //  2097152 bf16
  u16* wvb  = wkb + 2097152;              //  2097152 bf16
  u16* wob  = wvb + 2097152;              //  4194304 bf16
  u16* pb   = wob + 4194304;              //    65536 bf16 (P hi | P lo)
  u16* hb   = kvst;                       // hidden bf16 alias; dead before chunk_kv
  u16* phik = (u16*)d_out;                // 32 MiB of d_out
  u16* vTb  = phik + 16777216;            // upper 32 MiB of d_out
  u16* attn = q;

  // 0) fp32 -> bf16 casts
  f2b<<<8192, 256, 0, stream>>>(hidden, hb);
  f2b<<<2048, 256, 0, stream>>>(wq, wqb);
  f2b<<<1024, 256, 0, stream>>>(wk, wkb);
  f2b<<<1024, 256, 0, stream>>>(wv, wvb);
  f2b<<<2048, 256, 0, stream>>>(wo, wob);
  f2b_split<<<128, 256, 0, stream>>>(proj, pb, pb + 32768);

  // 1) q,k projections
  gemm_bt_mfma<u16><<<dim3(16, 64), 256, 0, stream>>>(hb, wqb, q, 2048, 2048);
  gemm_bt_mfma<u16><<<dim3( 8, 64), 256, 0, stream>>>(hb, wkb, kv, 2048, 1024);

  // 2) RoPE in place
  rope_bf<<<32768, 256, 0, stream>>>(q, cosb, sinb, NH);
  rope_bf<<<16384, 256, 0, stream>>>(kv, cosb, sinb, NKV);

  // 3) feature maps (MFMA, split-P)
  init_gmax<<<1, 1, 0, stream>>>(gmax);
  sqsum_k<<<256, 256, 0, stream>>>(kv, sqv);
  feat_mfma<true ><<<1024, 256, 0, stream>>>(q,  pb, phiq, sqv, gmax);
  feat_mfma<false><<< 512, 256, 0, stream>>>(kv, pb, phik, sqv, gmax);
  feat_k_b<<<65536, 256, 0, stream>>>(phik, gmax);

  // 4) v projection into the dead k region; then V^T
  gemm_bt_mfma<u16><<<dim3( 8, 64), 256, 0, stream>>>(hb, wvb, kv, 2048, 1024);
  vtrans<<<dim3(64, 2, 16), 256, 0, stream>>>(kv, vTb);

  // 5) chunk states (KV^T layout) + exclusive prefixes
  chunk_kv<<<dim3(8, NCNK, NB*NKV), 256, 0, stream>>>(phik, kv, kvst, ksst);
  prefix_kv<<<dim3(128, NB*NKV), 256, 0, stream>>>(kvst);
  prefix_ks<<<NB*NKV, 256, 0, stream>>>(ksst);

  // 6) per-chunk causal linear attention (MFMA)
  attn_mfma<<<dim3(NCNK, NH, NB), 256, 0, stream>>>(phiq, phik, vTb, kvst, ksst, attn);

  // 7) output projection
  gemm_bt_mfma<float><<<dim3(16, 64), 256, 0, stream>>>(attn, wob, out, 2048, 2048);
}

// Round 3
// 730.527 us; speedup vs baseline: 4.5998x; 1.1066x over previous
//
#include <hip/hip_runtime.h>

#define NB 2
#define NS 4096
#define NH 16
#define NKV 8
#define ND 128
#define NM 256
#define NCNK 32

#define SCALE_A 0.29730177875068026f   // 128^-0.25
#define PHI_SCALE 0.0625f              // 256^-0.5
#define EPSF 1e-6f

typedef unsigned short u16;
typedef unsigned int u32;
typedef __attribute__((ext_vector_type(8))) short short8;
typedef __attribute__((ext_vector_type(4))) float f32x4;

// ---- bf16 <-> fp32 helpers --------------------------------------------------
static __device__ __forceinline__ float bfh(u16 v) {
  return __uint_as_float(((u32)v) << 16);
}
static __device__ __forceinline__ u32 f2bf1(float f) {
  u32 u = __float_as_uint(f);
  return (u + 0x7fffu + ((u >> 16) & 1u)) >> 16;
}
static __device__ __forceinline__ u32 pack2(float a, float b) {
  return f2bf1(a) | (f2bf1(b) << 16);
}
static __device__ __forceinline__ void unp8(uint4 p, float* f) {
  f[0] = __uint_as_float(p.x << 16); f[1] = __uint_as_float(p.x & 0xffff0000u);
  f[2] = __uint_as_float(p.y << 16); f[3] = __uint_as_float(p.y & 0xffff0000u);
  f[4] = __uint_as_float(p.z << 16); f[5] = __uint_as_float(p.z & 0xffff0000u);
  f[6] = __uint_as_float(p.w << 16); f[7] = __uint_as_float(p.w & 0xffff0000u);
}
static __device__ __forceinline__ void ld8(const u16* p, float* f) {
  unp8(*(const uint4*)p, f);
}
static __device__ __forceinline__ void ld8(const float* p, float* f) {
  const float4 a = *(const float4*)p;
  const float4 b = *(const float4*)(p + 4);
  f[0]=a.x; f[1]=a.y; f[2]=a.z; f[3]=a.w;
  f[4]=b.x; f[5]=b.y; f[6]=b.z; f[7]=b.w;
}
static __device__ __forceinline__ void st8(u16* p, const float* o) {
  uint4 w;
  w.x = pack2(o[0], o[1]); w.y = pack2(o[2], o[3]);
  w.z = pack2(o[4], o[5]); w.w = pack2(o[6], o[7]);
  *(uint4*)p = w;
}

static __device__ __forceinline__ unsigned f2key(float f) {
  unsigned u = __float_as_uint(f);
  return (u & 0x80000000u) ? ~u : (u | 0x80000000u);
}
static __device__ __forceinline__ float key2f(unsigned k) {
  return (k & 0x80000000u) ? __uint_as_float(k & 0x7fffffffu) : __uint_as_float(~k);
}

__global__ void fill_out_f32(float* __restrict__ out, float val)
{
  const size_t idx = (size_t)blockIdx.x * 256 + threadIdx.x;
  out[idx] = val;
}

// ---------------------------------------------------------------------------
// f32 -> bf16 cast, 8 elems/thread.
// ---------------------------------------------------------------------------
__global__ void f2b(const float* __restrict__ in, u16* __restrict__ out)
{
  const size_t i = (((size_t)blockIdx.x * 256) + threadIdx.x) * 8;
  float f[8];
  ld8(in + i, f);
  st8(out + i, f);
}

// f32 -> bf16 hi/lo split
__global__ void f2b_split(const float* __restrict__ in, u16* __restrict__ hi,
                          u16* __restrict__ lo)
{
  const size_t i = (size_t)blockIdx.x * 256 + threadIdx.x;
  const float f = in[i];
  const u16 h = (u16)f2bf1(f);
  hi[i] = h;
  lo[i] = (u16)f2bf1(f - bfh(h));
}

// ---------------------------------------------------------------------------
// MFMA NT GEMM (m97 structure): C[M,Nc] = A[M,K] @ B[Nc,K]^T.
// ---------------------------------------------------------------------------
#define GLL(gp, lp) \
  __builtin_amdgcn_global_load_lds( \
      (const __attribute__((address_space(1))) u32*)(gp), \
      (__attribute__((address_space(3))) u32*)(lp), 16, 0, 0)

static __device__ __forceinline__ void stc(float* p, float v) { *p = v; }
static __device__ __forceinline__ void stc(u16* p, float v)  { *p = (u16)f2bf1(v); }

template <class TO>
__global__ __launch_bounds__(256) void gemm_bt_mfma(
    const u16* __restrict__ A, const u16* __restrict__ B,
    TO* __restrict__ C, int K, int Nc)
{
  __shared__ u16 As[4096];   // [128 rows][32 k] bf16
  __shared__ u16 Bs[4096];
  const int t = threadIdx.x;
  const int lane = t & 63;
  const int wid = t >> 6;
  const int wr = wid >> 1, wc = wid & 1;

  int bid = blockIdx.y * gridDim.x + blockIdx.x;
  {
    const int nwg = gridDim.x * gridDim.y;
    const int qq = nwg >> 3, rr = nwg & 7;
    const int x = bid & 7, o = bid >> 3;
    bid = (x < rr ? x * (qq + 1) : rr * (qq + 1) + (x - rr) * qq) + o;
  }
  const int rowBase = (bid / gridDim.x) * 128;
  const int colBase = (bid % gridDim.x) * 128;

  const int e0 = t * 8;
  const int sk = (t & 3) * 8;
  const size_t g0 = (size_t)(rowBase + (t >> 2)) * K + sk;
  const size_t g1 = (size_t)(colBase + (t >> 2)) * K + sk;
  const size_t rstep = (size_t)K * 64;

  const int fr = lane & 15;
  const int fk = (lane >> 4) * 8;
  const u16* Ar = As + (wr * 64 + fr) * 32 + fk;
  const u16* Br = Bs + (wc * 64 + fr) * 32 + fk;

  f32x4 acc[4][4];
#pragma unroll
  for (int i = 0; i < 4; ++i)
#pragma unroll
    for (int j = 0; j < 4; ++j) acc[i][j] = (f32x4){0.f, 0.f, 0.f, 0.f};

  for (int k0 = 0; k0 < K; k0 += 32) {
    GLL(A + g0 + k0,         As + e0);
    GLL(A + g0 + rstep + k0, As + 2048 + e0);
    GLL(B + g1 + k0,         Bs + e0);
    GLL(B + g1 + rstep + k0, Bs + 2048 + e0);
    asm volatile("s_waitcnt vmcnt(0)" ::: "memory");
    __syncthreads();
    short8 a[4], b[4];
#pragma unroll
    for (int mi = 0; mi < 4; ++mi) a[mi] = *(const short8*)(Ar + mi * 512);
#pragma unroll
    for (int ni = 0; ni < 4; ++ni) b[ni] = *(const short8*)(Br + ni * 512);
#pragma unroll
    for (int mi = 0; mi < 4; ++mi)
#pragma unroll
      for (int ni = 0; ni < 4; ++ni)
        acc[mi][ni] = __builtin_amdgcn_mfma_f32_16x16x32_bf16(
            a[mi], b[ni], acc[mi][ni], 0, 0, 0);
    __syncthreads();
  }

  const int cr = (lane >> 4) * 4;
  const int cc = lane & 15;
#pragma unroll
  for (int mi = 0; mi < 4; ++mi) {
    const int r0 = rowBase + wr * 64 + mi * 16 + cr;
#pragma unroll
    for (int ni = 0; ni < 4; ++ni) {
      const int col = colBase + wc * 64 + ni * 16 + cc;
#pragma unroll
      for (int j = 0; j < 4; ++j)
        stc(C + (size_t)(r0 + j) * Nc + col, acc[mi][ni][j]);
    }
  }
}

// ---------------------------------------------------------------------------
// RoPE in place on bf16, rows of qkv: x[n*rstr + coff + h*ND + d]
// ---------------------------------------------------------------------------
__global__ void rope_bf(u16* __restrict__ x, const float* __restrict__ cosb,
                        const float* __restrict__ sinb, int nheads, int coff)
{
  const size_t idx = (size_t)blockIdx.x * blockDim.x + threadIdx.x;
  const int d = (int)(idx & 63);
  const size_t nh = idx >> 6;
  const int h = (int)(nh % nheads);
  const size_t n = nh / nheads;
  const float c1 = cosb[n * ND + d];
  const float s1 = sinb[n * ND + d];
  const float c2 = cosb[n * ND + d + 64];
  const float s2 = sinb[n * ND + d + 64];
  u16* p = x + n * 4096 + coff + h * ND + d;
  const float x1 = bfh(p[0]);
  const float x2 = bfh(p[64]);
  p[0]  = (u16)f2bf1(x1 * c1 - x2 * s1);
  p[64] = (u16)f2bf1(x2 * c2 + x1 * s2);
}

// ---------------------------------------------------------------------------
// sq[row] = 0.5 * SCALE_A^2 * ||k_row||^2 ; k rows live in qkv cols 2048..3071
// ---------------------------------------------------------------------------
__global__ void sqsum_k(const u16* __restrict__ X, float* __restrict__ sqv)
{
  const size_t row = (size_t)blockIdx.x * 256 + threadIdx.x;   // n*8 + kh
  const u16* p = X + (row >> 3) * 4096 + 2048 + (row & 7) * 128;
  float s = 0.f;
  for (int k = 0; k < 128; k += 8) {
    float f[8];
    ld8(p + k, f);
#pragma unroll
    for (int j = 0; j < 8; ++j) s += f[j] * f[j];
  }
  sqv[row] = 0.5f * SCALE_A * SCALE_A * s;
}

// ---------------------------------------------------------------------------
// MFMA feature-map GEMM, single pass with P-hi and P-lo both resident.
// X rows addressed as (row>>RSH)*4096 + COFF + (row&mask)*128.
// ---------------------------------------------------------------------------
template <bool IS_Q, int RSH, int COFF>
__global__ __launch_bounds__(256) void feat_mfma(
    const u16* __restrict__ X, const u16* __restrict__ Pb,
    u16* __restrict__ U, const float* __restrict__ sqv,
    unsigned* __restrict__ gmax)
{
  __shared__ u16 As[4096];   // [128][32]
  __shared__ u16 Bh[8192];   // [256][32]
  __shared__ u16 Bl[8192];   // [256][32]
  __shared__ float rmW[2][128];
  __shared__ float wmax[4];
  const int t = threadIdx.x;
  const int lane = t & 63, wid = t >> 6;
  const int wr = wid >> 1, wc = wid & 1;
  const int fr = lane & 15, fk = (lane >> 4) * 8;
  const int cr = (lane >> 4) * 4, cc = lane & 15;
  const int sr = t >> 2, sk = (t & 3) * 8, e0 = t * 8;
  const int rowBase = blockIdx.x * 128;
  const int MASK = (1 << RSH) - 1;
  const u16* Pl = Pb + NM * 128;

  const int ga = rowBase + sr, gb = rowBase + sr + 64;
  const size_t xa = (size_t)(ga >> RSH) * 4096 + COFF + (size_t)(ga & MASK) * 128 + sk;
  const size_t xb = (size_t)(gb >> RSH) * 4096 + COFF + (size_t)(gb & MASK) * 128 + sk;

  f32x4 acc[4][8];
#pragma unroll
  for (int i = 0; i < 4; ++i)
#pragma unroll
    for (int j = 0; j < 8; ++j) acc[i][j] = (f32x4){0.f, 0.f, 0.f, 0.f};

  for (int k0 = 0; k0 < 128; k0 += 32) {
    GLL(X + xa + k0, As + e0);
    GLL(X + xb + k0, As + 2048 + e0);
#pragma unroll
    for (int qq = 0; qq < 4; ++qq) {
      GLL(Pb + (size_t)(sr + qq*64) * 128 + k0 + sk, Bh + qq*2048 + e0);
      GLL(Pl + (size_t)(sr + qq*64) * 128 + k0 + sk, Bl + qq*2048 + e0);
    }
    asm volatile("s_waitcnt vmcnt(0)" ::: "memory");
    __syncthreads();
    short8 a[4];
#pragma unroll
    for (int mi = 0; mi < 4; ++mi)
      a[mi] = *(const short8*)(As + (wr*64 + mi*16 + fr)*32 + fk);
    {
      short8 bb[8];
#pragma unroll
      for (int ni = 0; ni < 8; ++ni)
        bb[ni] = *(const short8*)(Bh + (wc*128 + ni*16 + fr)*32 + fk);
#pragma unroll
      for (int mi = 0; mi < 4; ++mi)
#pragma unroll
        for (int ni = 0; ni < 8; ++ni)
          acc[mi][ni] = __builtin_amdgcn_mfma_f32_16x16x32_bf16(
              a[mi], bb[ni], acc[mi][ni], 0, 0, 0);
    }
    {
      short8 bb[8];
#pragma unroll
      for (int ni = 0; ni < 8; ++ni)
        bb[ni] = *(const short8*)(Bl + (wc*128 + ni*16 + fr)*32 + fk);
#pragma unroll
      for (int mi = 0; mi < 4; ++mi)
#pragma unroll
        for (int ni = 0; ni < 8; ++ni)
          acc[mi][ni] = __builtin_amdgcn_mfma_f32_16x16x32_bf16(
              a[mi], bb[ni], acc[mi][ni], 0, 0, 0);
    }
    __syncthreads();
  }

  if (IS_Q) {
#pragma unroll
    for (int mi = 0; mi < 4; ++mi)
#pragma unroll
      for (int j = 0; j < 4; ++j) {
        float m = acc[mi][0][j];
#pragma unroll
        for (int ni = 1; ni < 8; ++ni) m = fmaxf(m, acc[mi][ni][j]);
        m = fmaxf(m, __shfl_xor(m, 1));
        m = fmaxf(m, __shfl_xor(m, 2));
        m = fmaxf(m, __shfl_xor(m, 4));
        m = fmaxf(m, __shfl_xor(m, 8));
        const int r = wr*64 + mi*16 + cr + j;
        if (cc == 0) rmW[wc][r] = m;
      }
    __syncthreads();
#pragma unroll
    for (int mi = 0; mi < 4; ++mi)
#pragma unroll
      for (int j = 0; j < 4; ++j) {
        const int r = wr*64 + mi*16 + cr + j;
        const float mr = fmaxf(rmW[0][r], rmW[1][r]);
        u16* up = U + (size_t)(rowBase + r) * NM + wc*128 + cc;
#pragma unroll
        for (int ni = 0; ni < 8; ++ni) {
          const float phi = expf(SCALE_A * (acc[mi][ni][j] - mr)) * PHI_SCALE + EPSF;
          up[ni*16] = (u16)f2bf1(phi);
        }
      }
  } else {
    float lmax = -1e30f;
#pragma unroll
    for (int mi = 0; mi < 4; ++mi)
#pragma unroll
      for (int j = 0; j < 4; ++j) {
        const int r = wr*64 + mi*16 + cr + j;
        const float sq = sqv[rowBase + r];
#pragma unroll
        for (int ni = 0; ni < 8; ++ni) {
          const float z = SCALE_A * acc[mi][ni][j] - sq;
          acc[mi][ni][j] = z;
          lmax = fmaxf(lmax, z);
        }
      }
    lmax = fmaxf(lmax, __shfl_xor(lmax, 1));
    lmax = fmaxf(lmax, __shfl_xor(lmax, 2));
    lmax = fmaxf(lmax, __shfl_xor(lmax, 4));
    lmax = fmaxf(lmax, __shfl_xor(lmax, 8));
    lmax = fmaxf(lmax, __shfl_xor(lmax, 16));
    lmax = fmaxf(lmax, __shfl_xor(lmax, 32));
    if (lane == 0) wmax[wid] = lmax;
    __syncthreads();
    if (t == 0) {
      const float bm = fmaxf(fmaxf(wmax[0], wmax[1]), fmaxf(wmax[2], wmax[3]));
      atomicMax(gmax, f2key(bm));
    }
#pragma unroll
    for (int mi = 0; mi < 4; ++mi)
#pragma unroll
      for (int j = 0; j < 4; ++j) {
        const int r = wr*64 + mi*16 + cr + j;
        u16* up = U + (size_t)(rowBase + r) * NM + wc*128 + cc;
#pragma unroll
        for (int ni = 0; ni < 8; ++ni)
          up[ni*16] = (u16)f2bf1(expf(acc[mi][ni][j]));
      }
  }
}

__global__ void init_gmax(unsigned* g) { *g = 0u; }

__global__ void feat_k_b(u16* __restrict__ u, const unsigned* __restrict__ gmax)
{
  const size_t idx = (size_t)blockIdx.x * blockDim.x + threadIdx.x;
  const float eg = expf(-key2f(*gmax));
  const float e = bfh(u[idx]);
  u[idx] = (u16)f2bf1(e * eg * PHI_SCALE + EPSF);
}

// ---------------------------------------------------------------------------
// V transpose: qkv v-part (cols 3072..4095) -> vT[b][kh][d][s]
// ---------------------------------------------------------------------------
__global__ __launch_bounds__(256) void vtrans(const u16* __restrict__ v,
                                              u16* __restrict__ vT)
{
  const int s0 = blockIdx.x * 64;
  const int d0 = blockIdx.y * 64;
  const int bkv = blockIdx.z;
  const int b = bkv >> 3, kh = bkv & 7;
  const int t = threadIdx.x;
  __shared__ u16 Tt[64][80];
  const int sl = t >> 3;          // 0..31
  const int ds = (t & 7) * 8;
#pragma unroll
  for (int r = 0; r < 2; ++r) {
    const u16* src = v + (size_t)(b*NS + s0 + r*32 + sl) * 4096 + 3072 + kh*128 + d0 + ds;
    *(uint4*)&Tt[r*32 + sl][ds] = *(const uint4*)src;
  }
  __syncthreads();
#pragma unroll
  for (int r = 0; r < 2; ++r) {
    const int dl = r*32 + sl;
    u16 tmp[8];
#pragma unroll
    for (int j = 0; j < 8; ++j) tmp[j] = Tt[ds + j][dl];
    u16* dst = vT + (((size_t)(b*NKV + kh) * ND) + d0 + dl) * NS + s0 + ds;
    *(uint4*)dst = *(uint4*)tmp;
  }
}

// ---------------------------------------------------------------------------
// Per-chunk k-sums (raw, prefix applied later by prefix_ks).
// ---------------------------------------------------------------------------
__global__ __launch_bounds__(256) void ksum_chunk(const u16* __restrict__ phik,
                                                  float* __restrict__ ksst)
{
  const int c = blockIdx.x, bkv = blockIdx.y;
  const int b = bkv >> 3, kh = bkv & 7;
  const int m = threadIdx.x;
  const size_t base = ((size_t)(b*NS + c*128) * NKV + kh) * NM + m;
  float s = 0.f;
  for (int i = 0; i < 128; ++i) s += bfh(phik[base + (size_t)i * (NKV*NM)]);
  ksst[((size_t)bkv * NCNK + c) * NM + m] = s;
}

// ---------------------------------------------------------------------------
// MFMA per-chunk KV state: kvT[bkv][c][d][m] = sum_i vT[d, c*128+i]*phik[i, m].
// A = vT rows (GLL); B = phik LDS-transposed via coalesced reg-stage with
// 16B-block XOR swizzle q^=(m>>1)&3 (self-inverse, applied on write & read).
// ---------------------------------------------------------------------------
__global__ __launch_bounds__(256) void chunk_kv_mfma(
    const u16* __restrict__ phik, const u16* __restrict__ vT,
    u16* __restrict__ kvT)
{
  const int c = blockIdx.x, bkv = blockIdx.y;
  const int b = bkv >> 3, kh = bkv & 7;
  const int t = threadIdx.x;
  const int lane = t & 63, wid = t >> 6;
  const int wr = wid >> 1, wc = wid & 1;
  const int fr = lane & 15, fk = (lane >> 4) * 8;
  const int cr = (lane >> 4) * 4, cc = lane & 15;
  const int sr = t >> 2, sk = (t & 3) * 8, e0 = t * 8;

  __shared__ u16 As[4096];      // [128 d][32 i]
  __shared__ u16 Bs[8192];      // [256 m][32 i], 16B-block swizzled

  const size_t vt_off = ((size_t)(b*NKV + kh) * ND) * NS + (size_t)c * 128;
  const size_t pk_row0 = ((size_t)(b*NS + c*128) * NKV + kh) * NM;
  const size_t pk_rstr = (size_t)NKV * NM;

  f32x4 acc[4][8];
#pragma unroll
  for (int i = 0; i < 4; ++i)
#pragma unroll
    for (int j = 0; j < 8; ++j) acc[i][j] = (f32x4){0.f, 0.f, 0.f, 0.f};

  const int m = t;
  const int sw = (m >> 1) & 3;

  for (int i0 = 0; i0 < 128; i0 += 32) {
    __syncthreads();   // previous step's fragments consumed
    GLL(vT + vt_off + (size_t)sr * NS + i0 + sk,        As + e0);
    GLL(vT + vt_off + (size_t)(sr + 64) * NS + i0 + sk, As + 2048 + e0);
    // B-stage: thread owns row m; reads 32 i-scalars (coalesced across threads)
    u16 rowv[32];
#pragma unroll
    for (int j = 0; j < 32; ++j)
      rowv[j] = phik[pk_row0 + (size_t)(i0 + j) * pk_rstr + m];
    u16* brow = Bs + m * 32;
#pragma unroll
    for (int q = 0; q < 4; ++q)
      *(uint4*)(brow + ((q ^ sw) * 8)) = *(const uint4*)(rowv + q*8);
    asm volatile("s_waitcnt vmcnt(0)" ::: "memory");
    __syncthreads();
    short8 a[4], bb[8];
#pragma unroll
    for (int mi = 0; mi < 4; ++mi)
      a[mi] = *(const short8*)(As + (wr*64 + mi*16 + fr)*32 + fk);
#pragma unroll
    for (int ni = 0; ni < 8; ++ni) {
      const int mrow = wc*128 + ni*16 + fr;
      const int q = fk >> 3;
      bb[ni] = *(const short8*)(Bs + mrow*32 + ((q ^ ((mrow >> 1) & 3)) << 3));
    }
#pragma unroll
    for (int mi = 0; mi < 4; ++mi)
#pragma unroll
      for (int ni = 0; ni < 8; ++ni)
        acc[mi][ni] = __builtin_amdgcn_mfma_f32_16x16x32_bf16(
            a[mi], bb[ni], acc[mi][ni], 0, 0, 0);
  }

  const size_t kv_off = ((size_t)bkv * NCNK + c) * (size_t)(ND*NM);
#pragma unroll
  for (int mi = 0; mi < 4; ++mi)
#pragma unroll
    for (int j = 0; j < 4; ++j) {
      const int d = wr*64 + mi*16 + cr + j;
#pragma unroll
      for (int ni = 0; ni < 8; ++ni) {
        const int mm = wc*128 + ni*16 + cc;
        kvT[kv_off + (size_t)d * NM + mm] = (u16)f2bf1(acc[mi][ni][j]);
      }
    }
}

// Exclusive prefix over the 32 chunks (elementwise walk, bf16 storage).
__global__ void prefix_kv(u16* __restrict__ kvst)
{
  const int md = blockIdx.x * 256 + threadIdx.x;        // 0..32767
  const size_t base = (size_t)blockIdx.y * NCNK * (NM*ND) + md;
  float carry = 0.f;
  for (int c = 0; c < NCNK; ++c) {
    const size_t a = base + (size_t)c * (NM*ND);
    const float val = bfh(kvst[a]);
    kvst[a] = (u16)f2bf1(carry);
    carry += val;
  }
}

__global__ void prefix_ks(float* __restrict__ ksst)
{
  const int m = threadIdx.x;
  const size_t base = (size_t)blockIdx.x * NCNK * NM + m;
  float carry = 0.f;
  for (int c = 0; c < NCNK; ++c) {
    const size_t a = base + (size_t)c * NM;
    const float val = ksst[a];
    ksst[a] = carry;
    carry += val;
  }
}

// ---------------------------------------------------------------------------
// MFMA per-chunk causal linear attention (unchanged from round 1).
// ---------------------------------------------------------------------------
__global__ __launch_bounds__(256) void attn_mfma(
    const u16* __restrict__ phiq, const u16* __restrict__ phik,
    const u16* __restrict__ vT, const u16* __restrict__ kvT,
    const float* __restrict__ kspre, u16* __restrict__ attn)
{
  const int c = blockIdx.x, h = blockIdx.y, b = blockIdx.z;
  const int kh = h >> 1;                 // groups = 2
  const int bkv = b * NKV + kh;
  const int t = threadIdx.x;
  const int lane = t & 63, wid = t >> 6;
  const int wr = wid >> 1, wc = wid & 1;
  const int fr = lane & 15, fk = (lane >> 4) * 8;
  const int cr = (lane >> 4) * 4, cc = lane & 15;
  const int sr = t >> 2, sk = (t & 3) * 8, e0 = t * 8;

  __shared__ u16 As[4096];      // [128][32]
  __shared__ u16 Bs[4096];      // [128][32]
  __shared__ u16 Sl[16384];     // [128][128] swizzled bf16
  __shared__ float den_l[128];
  __shared__ float ks_l[256];

  const size_t pq_off = ((size_t)(b*NS + c*128) * NH  + h)  * NM;
  const size_t pk_off = ((size_t)(b*NS + c*128) * NKV + kh) * NM;
  const size_t vt_off = ((size_t)(b*NKV + kh) * ND) * (size_t)NS + (size_t)c * 128;
  const size_t kv_off = ((size_t)bkv * NCNK + c) * (size_t)(ND*NM);

  if (t < 128) den_l[t] = 0.f;
  ks_l[t] = kspre[((size_t)bkv * NCNK + c) * NM + t];

  const u16* Arp = As + (wr*64 + fr)*32 + fk;
  const u16* Brp = Bs + (wc*64 + fr)*32 + fk;

  // ---- phase A: S = Pq @ Pk^T -------------------------------------------
  f32x4 accS[4][4];
#pragma unroll
  for (int i = 0; i < 4; ++i)
#pragma unroll
    for (int j = 0; j < 4; ++j) accS[i][j] = (f32x4){0.f, 0.f, 0.f, 0.f};

  for (int k0 = 0; k0 < NM; k0 += 32) {
    GLL(phiq + pq_off + (size_t)sr * 4096 + k0 + sk,        As + e0);
    GLL(phiq + pq_off + (size_t)(sr + 64) * 4096 + k0 + sk, As + 2048 + e0);
    GLL(phik + pk_off + (size_t)sr * 2048 + k0 + sk,        Bs + e0);
    GLL(phik + pk_off + (size_t)(sr + 64) * 2048 + k0 + sk, Bs + 2048 + e0);
    asm volatile("s_waitcnt vmcnt(0)" ::: "memory");
    __syncthreads();
    short8 a[4], bb[4];
#pragma unroll
    for (int mi = 0; mi < 4; ++mi) a[mi] = *(const short8*)(Arp + mi*512);
#pragma unroll
    for (int ni = 0; ni < 4; ++ni) bb[ni] = *(const short8*)(Brp + ni*512);
#pragma unroll
    for (int mi = 0; mi < 4; ++mi)
#pragma unroll
      for (int ni = 0; ni < 4; ++ni)
        accS[mi][ni] = __builtin_amdgcn_mfma_f32_16x16x32_bf16(
            a[mi], bb[ni], accS[mi][ni], 0, 0, 0);
    __syncthreads();
  }

  // ---- mask + rowsum + write S to swizzled LDS ---------------------------
#pragma unroll
  for (int mi = 0; mi < 4; ++mi)
#pragma unroll
    for (int j = 0; j < 4; ++j) {
      const int r = wr*64 + mi*16 + cr + j;
      float s = 0.f;
#pragma unroll
      for (int ni = 0; ni < 4; ++ni) {
        const int cl = wc*64 + ni*16 + cc;
        float vv = accS[mi][ni][j];
        vv = (cl > r) ? 0.f : vv;
        accS[mi][ni][j] = vv;
        s += vv;
      }
      s += __shfl_xor(s, 1); s += __shfl_xor(s, 2);
      s += __shfl_xor(s, 4); s += __shfl_xor(s, 8);
      if (cc == 0) atomicAdd(&den_l[r], s);
#pragma unroll
      for (int ni = 0; ni < 4; ++ni) {
        const int cl = wc*64 + ni*16 + cc;
        u32 bo = ((u32)r << 8) + ((u32)cl << 1);
        bo ^= (u32)(r & 7) << 4;
        *(u16*)((char*)Sl + bo) = (u16)f2bf1(accS[mi][ni][j]);
      }
    }
  __syncthreads();

  // ---- phase C: acc2 = S @ V  (B-rows = vT[d][s]) ------------------------
  f32x4 acc2[4][4];
#pragma unroll
  for (int i = 0; i < 4; ++i)
#pragma unroll
    for (int j = 0; j < 4; ++j) acc2[i][j] = (f32x4){0.f, 0.f, 0.f, 0.f};

  for (int j0 = 0; j0 < 128; j0 += 32) {
    GLL(vT + vt_off + (size_t)sr * NS + j0 + sk,        Bs + e0);
    GLL(vT + vt_off + (size_t)(sr + 64) * NS + j0 + sk, Bs + 2048 + e0);
    asm volatile("s_waitcnt vmcnt(0)" ::: "memory");
    __syncthreads();
    short8 a[4], bb[4];
#pragma unroll
    for (int mi = 0; mi < 4; ++mi) {
      u32 bo = ((u32)(wr*64 + mi*16 + fr) << 8) + ((u32)(j0 + fk) << 1);
      bo ^= (u32)(fr & 7) << 4;
      a[mi] = *(const short8*)((const char*)Sl + bo);
    }
#pragma unroll
    for (int ni = 0; ni < 4; ++ni) bb[ni] = *(const short8*)(Brp + ni*512);
#pragma unroll
    for (int mi = 0; mi < 4; ++mi)
#pragma unroll
      for (int ni = 0; ni < 4; ++ni)
        acc2[mi][ni] = __builtin_amdgcn_mfma_f32_16x16x32_bf16(
            a[mi], bb[ni], acc2[mi][ni], 0, 0, 0);
    __syncthreads();
  }

  // ---- phase D: acc2 += Pq @ KVpre ; den += Pq . ks_prefix ---------------
  for (int m0 = 0; m0 < NM; m0 += 32) {
    GLL(phiq + pq_off + (size_t)sr * 4096 + m0 + sk,        As + e0);
    GLL(phiq + pq_off + (size_t)(sr + 64) * 4096 + m0 + sk, As + 2048 + e0);
    GLL(kvT + kv_off + (size_t)sr * NM + m0 + sk,           Bs + e0);
    GLL(kvT + kv_off + (size_t)(sr + 64) * NM + m0 + sk,    Bs + 2048 + e0);
    asm volatile("s_waitcnt vmcnt(0)" ::: "memory");
    __syncthreads();
    short8 a[4], bb[4];
#pragma unroll
    for (int mi = 0; mi < 4; ++mi) a[mi] = *(const short8*)(Arp + mi*512);
#pragma unroll
    for (int ni = 0; ni < 4; ++ni) bb[ni] = *(const short8*)(Brp + ni*512);
#pragma unroll
    for (int mi = 0; mi < 4; ++mi)
#pragma unroll
      for (int ni = 0; ni < 4; ++ni)
        acc2[mi][ni] = __builtin_amdgcn_mfma_f32_16x16x32_bf16(
            a[mi], bb[ni], acc2[mi][ni], 0, 0, 0);
    {
      const int pr = t >> 1;
      const int pm = (t & 1) * 16;
      float xf[16];
      unp8(*(const uint4*)(As + pr*32 + pm), xf);
      unp8(*(const uint4*)(As + pr*32 + pm + 8), xf + 8);
      float s = 0.f;
#pragma unroll
      for (int jj = 0; jj < 16; ++jj) s += xf[jj] * ks_l[m0 + pm + jj];
      s += __shfl_xor(s, 1);
      if (!(t & 1)) atomicAdd(&den_l[pr], s);
    }
    __syncthreads();
  }

  // ---- epilogue: out = acc2 / (den + eps) --------------------------------
#pragma unroll
  for (int mi = 0; mi < 4; ++mi)
#pragma unroll
    for (int j = 0; j < 4; ++j) {
      const int r = wr*64 + mi*16 + cr + j;
      const float inv = 1.0f / (den_l[r] + EPSF);
      u16* op = attn + ((size_t)(b*NS + c*128 + r) * NH + h) * ND + wc*64 + cc;
#pragma unroll
      for (int ni = 0; ni < 4; ++ni)
        op[ni*16] = (u16)f2bf1(acc2[mi][ni][j] * inv);
    }
}

// ---------------------------------------------------------------------------
extern "C" void kernel_launch(void* const* d_in, const int* in_sizes, int n_in,
                              void* d_out, int out_size, void* d_ws, size_t ws_size,
                              hipStream_t stream)
{
  const float* hidden = (const float*)d_in[0];
  const float* cosb   = (const float*)d_in[1];
  const float* sinb   = (const float*)d_in[2];
  const float* wq     = (const float*)d_in[3];
  const float* wk     = (const float*)d_in[4];
  const float* wv     = (const float*)d_in[5];
  const float* wo     = (const float*)d_in[6];
  const float* proj   = (const float*)d_in[7];
  float* out = (float*)d_out;

  const size_t MiB = 1024ull * 1024ull;
  if (ws_size < 186ull * MiB) {        // need ~185 MiB; certified >=192 MiB
    fill_out_f32<<<65536, 256, 0, stream>>>(out, 400.f);
    return;
  }

  // workspace (~185 MiB):
  //   qkv(64M) | phiq(64M) | kvst(32M, aliased as hb pre-chunk) | ksst | misc
  //   | wqkvb(16M) | wob(8M) | pb(0.125M)
  u16* qkv  = (u16*)d_ws;                 // 33554432 bf16 [8192][4096]
  u16* phiq = qkv  + 33554432;            // 33554432 bf16
  u16* kvst = phiq + 33554432;            // 16777216 bf16 (KV^T chunk states)
  float* ksst = (float*)(kvst + 16777216);//   131072 f32
  unsigned* gmax = (unsigned*)(ksst + 131072);
  float* sqv = (float*)(gmax + 64);       //    65536 f32
  u16* wqkvb = (u16*)(sqv + 65536);       //  8388608 bf16 [4096][2048]
  u16* wob  = wqkvb + 8388608;            //  4194304 bf16
  u16* pb   = wob + 4194304;              //    65536 bf16 (P hi | P lo)
  u16* hb   = kvst;                       // hidden bf16 alias; dead before chunk
  u16* phik = (u16*)d_out;                // 32 MiB of d_out
  u16* vTb  = phik + 16777216;            // upper 32 MiB of d_out
  u16* attn = qkv;                        // attn overwrites qkv (dead by then)

  // 0) fp32 -> bf16 casts
  f2b<<<8192, 256, 0, stream>>>(hidden, hb);
  f2b<<<2048, 256, 0, stream>>>(wq, wqkvb);
  f2b<<<1024, 256, 0, stream>>>(wk, wqkvb + 2048*2048);
  f2b<<<1024, 256, 0, stream>>>(wv, wqkvb + 3072*2048);
  f2b<<<2048, 256, 0, stream>>>(wo, wob);
  f2b_split<<<128, 256, 0, stream>>>(proj, pb, pb + 32768);

  // 1) fused qkv projection: [8192][4096] = hb @ wqkvb^T
  gemm_bt_mfma<u16><<<dim3(32, 64), 256, 0, stream>>>(hb, wqkvb, qkv, 2048, 4096);

  // 2) V transpose (v needs no RoPE), then RoPE on q,k in place
  vtrans<<<dim3(64, 2, 16), 256, 0, stream>>>(qkv, vTb);
  rope_bf<<<32768, 256, 0, stream>>>(qkv, cosb, sinb, NH, 0);
  rope_bf<<<16384, 256, 0, stream>>>(qkv, cosb, sinb, NKV, 2048);

  // 3) feature maps (MFMA, single-pass hi+lo)
  init_gmax<<<1, 1, 0, stream>>>(gmax);
  sqsum_k<<<256, 256, 0, stream>>>(qkv, sqv);
  feat_mfma<true , 4, 0   ><<<1024, 256, 0, stream>>>(qkv, pb, phiq, sqv, gmax);
  feat_mfma<false, 3, 2048><<< 512, 256, 0, stream>>>(qkv, pb, phik, sqv, gmax);
  feat_k_b<<<65536, 256, 0, stream>>>(phik, gmax);

  // 4) chunk states (MFMA, KV^T layout) + k-sums + exclusive prefixes
  chunk_kv_mfma<<<dim3(NCNK, NB*NKV), 256, 0, stream>>>(phik, vTb, kvst);
  ksum_chunk<<<dim3(NCNK, NB*NKV), 256, 0, stream>>>(phik, ksst);
  prefix_kv<<<dim3(128, NB*NKV), 256, 0, stream>>>(kvst);
  prefix_ks<<<NB*NKV, 256, 0, stream>>>(ksst);

  // 5) per-chunk causal linear attention (MFMA); writes attn into qkv region
  attn_mfma<<<dim3(NCNK, NH, NB), 256, 0, stream>>>(phiq, phik, vTb, kvst, ksst, attn);

  // 6) output projection
  gemm_bt_mfma<float><<<dim3(16, 64), 256, 0, stream>>>(attn, wob, out, 2048, 2048);
}

// Round 4
// 617.294 us; speedup vs baseline: 5.4436x; 1.1834x over previous
//
#include <hip/hip_runtime.h>

#define NB 2
#define NS 4096
#define NH 16
#define NKV 8
#define ND 128
#define NM 256
#define NCNK 32

#define SCALE_A 0.29730177875068026f   // 128^-0.25
#define PHI_SCALE 0.0625f              // 256^-0.5
#define EPSF 1e-6f

typedef unsigned short u16;
typedef unsigned int u32;
typedef __attribute__((ext_vector_type(8))) short short8;
typedef __attribute__((ext_vector_type(4))) float f32x4;

// ---- bf16 <-> fp32 helpers --------------------------------------------------
static __device__ __forceinline__ float bfh(u16 v) {
  return __uint_as_float(((u32)v) << 16);
}
static __device__ __forceinline__ u32 f2bf1(float f) {
  u32 u = __float_as_uint(f);
  return (u + 0x7fffu + ((u >> 16) & 1u)) >> 16;
}
static __device__ __forceinline__ u32 pack2(float a, float b) {
  return f2bf1(a) | (f2bf1(b) << 16);
}
static __device__ __forceinline__ void unp8(uint4 p, float* f) {
  f[0] = __uint_as_float(p.x << 16); f[1] = __uint_as_float(p.x & 0xffff0000u);
  f[2] = __uint_as_float(p.y << 16); f[3] = __uint_as_float(p.y & 0xffff0000u);
  f[4] = __uint_as_float(p.z << 16); f[5] = __uint_as_float(p.z & 0xffff0000u);
  f[6] = __uint_as_float(p.w << 16); f[7] = __uint_as_float(p.w & 0xffff0000u);
}
static __device__ __forceinline__ void ld8(const u16* p, float* f) {
  unp8(*(const uint4*)p, f);
}
static __device__ __forceinline__ void ld8(const float* p, float* f) {
  const float4 a = *(const float4*)p;
  const float4 b = *(const float4*)(p + 4);
  f[0]=a.x; f[1]=a.y; f[2]=a.z; f[3]=a.w;
  f[4]=b.x; f[5]=b.y; f[6]=b.z; f[7]=b.w;
}
static __device__ __forceinline__ void st8(u16* p, const float* o) {
  uint4 w;
  w.x = pack2(o[0], o[1]); w.y = pack2(o[2], o[3]);
  w.z = pack2(o[4], o[5]); w.w = pack2(o[6], o[7]);
  *(uint4*)p = w;
}

static __device__ __forceinline__ unsigned f2key(float f) {
  unsigned u = __float_as_uint(f);
  return (u & 0x80000000u) ? ~u : (u | 0x80000000u);
}
static __device__ __forceinline__ float key2f(unsigned k) {
  return (k & 0x80000000u) ? __uint_as_float(k & 0x7fffffffu) : __uint_as_float(~k);
}

__global__ void fill_out_f32(float* __restrict__ out, float val)
{
  const size_t idx = (size_t)blockIdx.x * 256 + threadIdx.x;
  out[idx] = val;
}

// ---------------------------------------------------------------------------
// f32 -> bf16 cast, 8 elems/thread.
// ---------------------------------------------------------------------------
__global__ void f2b(const float* __restrict__ in, u16* __restrict__ out)
{
  const size_t i = (((size_t)blockIdx.x * 256) + threadIdx.x) * 8;
  float f[8];
  ld8(in + i, f);
  st8(out + i, f);
}

// f32 -> bf16 hi/lo split
__global__ void f2b_split(const float* __restrict__ in, u16* __restrict__ hi,
                          u16* __restrict__ lo)
{
  const size_t i = (size_t)blockIdx.x * 256 + threadIdx.x;
  const float f = in[i];
  const u16 h = (u16)f2bf1(f);
  hi[i] = h;
  lo[i] = (u16)f2bf1(f - bfh(h));
}

#define GLL(gp, lp) \
  __builtin_amdgcn_global_load_lds( \
      (const __attribute__((address_space(1))) u32*)(gp), \
      (__attribute__((address_space(3))) u32*)(lp), 16, 0, 0)

static __device__ __forceinline__ void stc(float* p, float v) { *p = v; }
static __device__ __forceinline__ void stc(u16* p, float v)  { *p = (u16)f2bf1(v); }

static __device__ __forceinline__ void bar_f() {
  asm volatile("" ::: "memory");
  __builtin_amdgcn_s_barrier();
  asm volatile("" ::: "memory");
}
static __device__ __forceinline__ void lgkm0_f() {
  asm volatile("s_waitcnt lgkmcnt(0)" ::: "memory");
  __builtin_amdgcn_sched_barrier(0);
}

// ---------------------------------------------------------------------------
// 256x256 8-phase MFMA NT GEMM: C[M,Nc] = A[M,K] @ B[Nc,K]^T, bf16 in.
// BK=64, 512 thr (8 waves = 2x4 per quadrant), LDS 128 KB double buffer.
// Per phase = one 128x128 C-quadrant x K=64; counted vmcnt(4) once per K-tile.
// T2 XOR swizzle: physical 16B block = logical ^ (row&7) (inverse-permuted
// global source + swizzled ds_read). Requires M%256==0, Nc%256==0, K%64==0,
// K>=128.
// ---------------------------------------------------------------------------
template <class TO>
__global__ __launch_bounds__(512, 2) void gemm_bt_256(
    const u16* __restrict__ A, const u16* __restrict__ B,
    TO* __restrict__ C, int K, int Nc)
{
  __shared__ short8 ldsv[8192];          // 128 KB
  u16* Abuf = (u16*)ldsv;                // [2][256 rows][64 k]
  u16* Bbuf = (u16*)ldsv + 32768;        // [2][256 cols][64 k]

  const int t = threadIdx.x;
  const int lane = t & 63;
  const int wid = t >> 6;
  const int wr = wid >> 2;               // 0..1 (M sub-row in quadrant)
  const int wc = wid & 3;                // 0..3 (N sub-col in quadrant)

  int bid = blockIdx.y * gridDim.x + blockIdx.x;
  {
    const int nwg = gridDim.x * gridDim.y;
    const int qq = nwg >> 3, rr = nwg & 7;
    const int x = bid & 7, o = bid >> 3;
    bid = (x < rr ? x * (qq + 1) : rr * (qq + 1) + (x - rr) * qq) + o;
  }
  const int rowBase = (bid / gridDim.x) * 256;
  const int colBase = (bid % gridDim.x) * 256;
  const int NT = K >> 6;

  // staging geometry: thread t covers 16B block (row srow, block t&7) of a half
  const int srow = t >> 3;                               // 0..63
  const int scol = (((t & 7) ^ ((t >> 3) & 7)) << 3);    // inverse-swizzled k
  const int sld  = t * 8;                                // elem offset (j=0)

  // fragment read geometry
  const int frow = lane & 15;
  const int fkey = lane & 7;
  const int fql  = lane >> 4;            // 0..3

#define STAGE_A(bsel, h, u) do { \
    const u16* gp_ = A + (size_t)(rowBase + (h)*128 + srow) * K + (u)*64 + scol; \
    GLL(gp_,                Abuf + (bsel)*16384 + (h)*8192 + sld); \
    GLL(gp_ + (size_t)64*K, Abuf + (bsel)*16384 + (h)*8192 + 4096 + sld); \
  } while (0)
#define STAGE_B(bsel, h, u) do { \
    const u16* gp_ = B + (size_t)(colBase + (h)*128 + srow) * K + (u)*64 + scol; \
    GLL(gp_,                Bbuf + (bsel)*16384 + (h)*8192 + sld); \
    GLL(gp_ + (size_t)64*K, Bbuf + (bsel)*16384 + (h)*8192 + 4096 + sld); \
  } while (0)

  short8 af[4][2], b0[2][2], b1[2][2];

#define LDA(Mh, bsel) do { \
    _Pragma("unroll") for (int mi = 0; mi < 4; ++mi) \
    _Pragma("unroll") for (int ks = 0; ks < 2; ++ks) { \
      const int rib_ = (Mh)*128 + wr*64 + mi*16 + frow; \
      const int pb_ = (ks*4 + fql) ^ fkey; \
      af[mi][ks] = *(const short8*)(Abuf + (bsel)*16384 + rib_*64 + pb_*8); \
    } } while (0)
#define LDB(dst, Nh, bsel) do { \
    _Pragma("unroll") for (int ni = 0; ni < 2; ++ni) \
    _Pragma("unroll") for (int ks = 0; ks < 2; ++ks) { \
      const int rib_ = (Nh)*128 + wc*32 + ni*16 + frow; \
      const int pb_ = (ks*4 + fql) ^ fkey; \
      dst[ni][ks] = *(const short8*)(Bbuf + (bsel)*16384 + rib_*64 + pb_*8); \
    } } while (0)

  f32x4 acc[2][2][4][2];
#pragma unroll
  for (int a_ = 0; a_ < 2; ++a_)
#pragma unroll
    for (int b_ = 0; b_ < 2; ++b_)
#pragma unroll
      for (int m_ = 0; m_ < 4; ++m_)
#pragma unroll
        for (int n_ = 0; n_ < 2; ++n_)
          acc[a_][b_][m_][n_] = (f32x4){0.f, 0.f, 0.f, 0.f};

#define MMQ(Mh, Nh, bfr) do { \
    _Pragma("unroll") for (int mi = 0; mi < 4; ++mi) \
    _Pragma("unroll") for (int ni = 0; ni < 2; ++ni) \
    _Pragma("unroll") for (int ks = 0; ks < 2; ++ks) \
      acc[Mh][Nh][mi][ni] = __builtin_amdgcn_mfma_f32_16x16x32_bf16( \
          af[mi][ks], bfr[ni][ks], acc[Mh][Nh][mi][ni], 0, 0, 0); \
  } while (0)

  // ---- prologue: tile0 (4 halves) + A0,B0 of tile1; vmcnt(4) -> tile0 landed
  STAGE_A(0, 0, 0); STAGE_B(0, 0, 0); STAGE_A(0, 1, 0); STAGE_B(0, 1, 0);
  STAGE_A(1, 0, 1); STAGE_B(1, 0, 1);           // NT>=2 guaranteed (K>=128)
  asm volatile("s_waitcnt vmcnt(4)" ::: "memory");
  bar_f();

  for (int u = 0; u < NT; ++u) {
    const int bsel = u & 1, osel = bsel ^ 1;
    // ---- Q1: quadrant (M0,N0); stage A1(u+1)
    LDA(0, bsel); LDB(b0, 0, bsel);
    if (u + 1 < NT) STAGE_A(osel, 1, u + 1);
    bar_f(); lgkm0_f();
    __builtin_amdgcn_s_setprio(1); MMQ(0, 0, b0); __builtin_amdgcn_s_setprio(0);
    bar_f();
    // ---- Q2: quadrant (M0,N1); stage B1(u+1)
    LDB(b1, 1, bsel);
    if (u + 1 < NT) STAGE_B(osel, 1, u + 1);
    bar_f(); lgkm0_f();
    __builtin_amdgcn_s_setprio(1); MMQ(0, 1, b1); __builtin_amdgcn_s_setprio(0);
    bar_f();
    // ---- Q3: quadrant (M1,N0); stage A0(u+2)
    LDA(1, bsel);
    if (u + 2 < NT) STAGE_A(bsel, 0, u + 2);
    bar_f(); lgkm0_f();
    __builtin_amdgcn_s_setprio(1); MMQ(1, 0, b0); __builtin_amdgcn_s_setprio(0);
    bar_f();
    // ---- Q4: quadrant (M1,N1); stage B0(u+2); counted vmcnt (never 0)
    if (u + 2 < NT) STAGE_B(bsel, 0, u + 2);
    __builtin_amdgcn_s_setprio(1); MMQ(1, 1, b1); __builtin_amdgcn_s_setprio(0);
    asm volatile("s_waitcnt vmcnt(4)" ::: "memory");
    bar_f();
  }

  // ---- epilogue: C-write
  const int cr = (lane >> 4) * 4;
  const int cc = lane & 15;
#pragma unroll
  for (int Mh = 0; Mh < 2; ++Mh)
#pragma unroll
    for (int mi = 0; mi < 4; ++mi) {
      const int r0 = rowBase + Mh*128 + wr*64 + mi*16 + cr;
#pragma unroll
      for (int Nh = 0; Nh < 2; ++Nh)
#pragma unroll
        for (int ni = 0; ni < 2; ++ni) {
          const int col = colBase + Nh*128 + wc*32 + ni*16 + cc;
#pragma unroll
          for (int j = 0; j < 4; ++j)
            stc(C + (size_t)(r0 + j) * Nc + col, acc[Mh][Nh][mi][ni][j]);
        }
    }
#undef STAGE_A
#undef STAGE_B
#undef LDA
#undef LDB
#undef MMQ
}

// ---------------------------------------------------------------------------
// RoPE in place on bf16, rows of qkv: x[n*rstr + coff + h*ND + d]
// ---------------------------------------------------------------------------
__global__ void rope_bf(u16* __restrict__ x, const float* __restrict__ cosb,
                        const float* __restrict__ sinb, int nheads, int coff)
{
  const size_t idx = (size_t)blockIdx.x * blockDim.x + threadIdx.x;
  const int d = (int)(idx & 63);
  const size_t nh = idx >> 6;
  const int h = (int)(nh % nheads);
  const size_t n = nh / nheads;
  const float c1 = cosb[n * ND + d];
  const float s1 = sinb[n * ND + d];
  const float c2 = cosb[n * ND + d + 64];
  const float s2 = sinb[n * ND + d + 64];
  u16* p = x + n * 4096 + coff + h * ND + d;
  const float x1 = bfh(p[0]);
  const float x2 = bfh(p[64]);
  p[0]  = (u16)f2bf1(x1 * c1 - x2 * s1);
  p[64] = (u16)f2bf1(x2 * c2 + x1 * s2);
}

// ---------------------------------------------------------------------------
// sq[row] = 0.5 * SCALE_A^2 * ||k_row||^2 ; k rows live in qkv cols 2048..3071
// ---------------------------------------------------------------------------
__global__ void sqsum_k(const u16* __restrict__ X, float* __restrict__ sqv)
{
  const size_t row = (size_t)blockIdx.x * 256 + threadIdx.x;   // n*8 + kh
  const u16* p = X + (row >> 3) * 4096 + 2048 + (row & 7) * 128;
  float s = 0.f;
  for (int k = 0; k < 128; k += 8) {
    float f[8];
    ld8(p + k, f);
#pragma unroll
    for (int j = 0; j < 8; ++j) s += f[j] * f[j];
  }
  sqv[row] = 0.5f * SCALE_A * SCALE_A * s;
}

// ---------------------------------------------------------------------------
// MFMA feature-map GEMM, single pass with P-hi and P-lo both resident.
// X rows addressed as (row>>RSH)*4096 + COFF + (row&mask)*128.
// ---------------------------------------------------------------------------
template <bool IS_Q, int RSH, int COFF>
__global__ __launch_bounds__(256) void feat_mfma(
    const u16* __restrict__ X, const u16* __restrict__ Pb,
    u16* __restrict__ U, const float* __restrict__ sqv,
    unsigned* __restrict__ gmax)
{
  __shared__ u16 As[4096];   // [128][32]
  __shared__ u16 Bh[8192];   // [256][32]
  __shared__ u16 Bl[8192];   // [256][32]
  __shared__ float rmW[2][128];
  __shared__ float wmax[4];
  const int t = threadIdx.x;
  const int lane = t & 63, wid = t >> 6;
  const int wr = wid >> 1, wc = wid & 1;
  const int fr = lane & 15, fk = (lane >> 4) * 8;
  const int cr = (lane >> 4) * 4, cc = lane & 15;
  const int sr = t >> 2, sk = (t & 3) * 8, e0 = t * 8;
  const int rowBase = blockIdx.x * 128;
  const int MASK = (1 << RSH) - 1;
  const u16* Pl = Pb + NM * 128;

  const int ga = rowBase + sr, gb = rowBase + sr + 64;
  const size_t xa = (size_t)(ga >> RSH) * 4096 + COFF + (size_t)(ga & MASK) * 128 + sk;
  const size_t xb = (size_t)(gb >> RSH) * 4096 + COFF + (size_t)(gb & MASK) * 128 + sk;

  f32x4 acc[4][8];
#pragma unroll
  for (int i = 0; i < 4; ++i)
#pragma unroll
    for (int j = 0; j < 8; ++j) acc[i][j] = (f32x4){0.f, 0.f, 0.f, 0.f};

  for (int k0 = 0; k0 < 128; k0 += 32) {
    GLL(X + xa + k0, As + e0);
    GLL(X + xb + k0, As + 2048 + e0);
#pragma unroll
    for (int qq = 0; qq < 4; ++qq) {
      GLL(Pb + (size_t)(sr + qq*64) * 128 + k0 + sk, Bh + qq*2048 + e0);
      GLL(Pl + (size_t)(sr + qq*64) * 128 + k0 + sk, Bl + qq*2048 + e0);
    }
    asm volatile("s_waitcnt vmcnt(0)" ::: "memory");
    __syncthreads();
    short8 a[4];
#pragma unroll
    for (int mi = 0; mi < 4; ++mi)
      a[mi] = *(const short8*)(As + (wr*64 + mi*16 + fr)*32 + fk);
    {
      short8 bb[8];
#pragma unroll
      for (int ni = 0; ni < 8; ++ni)
        bb[ni] = *(const short8*)(Bh + (wc*128 + ni*16 + fr)*32 + fk);
#pragma unroll
      for (int mi = 0; mi < 4; ++mi)
#pragma unroll
        for (int ni = 0; ni < 8; ++ni)
          acc[mi][ni] = __builtin_amdgcn_mfma_f32_16x16x32_bf16(
              a[mi], bb[ni], acc[mi][ni], 0, 0, 0);
    }
    {
      short8 bb[8];
#pragma unroll
      for (int ni = 0; ni < 8; ++ni)
        bb[ni] = *(const short8*)(Bl + (wc*128 + ni*16 + fr)*32 + fk);
#pragma unroll
      for (int mi = 0; mi < 4; ++mi)
#pragma unroll
        for (int ni = 0; ni < 8; ++ni)
          acc[mi][ni] = __builtin_amdgcn_mfma_f32_16x16x32_bf16(
              a[mi], bb[ni], acc[mi][ni], 0, 0, 0);
    }
    __syncthreads();
  }

  if (IS_Q) {
#pragma unroll
    for (int mi = 0; mi < 4; ++mi)
#pragma unroll
      for (int j = 0; j < 4; ++j) {
        float m = acc[mi][0][j];
#pragma unroll
        for (int ni = 1; ni < 8; ++ni) m = fmaxf(m, acc[mi][ni][j]);
        m = fmaxf(m, __shfl_xor(m, 1));
        m = fmaxf(m, __shfl_xor(m, 2));
        m = fmaxf(m, __shfl_xor(m, 4));
        m = fmaxf(m, __shfl_xor(m, 8));
        const int r = wr*64 + mi*16 + cr + j;
        if (cc == 0) rmW[wc][r] = m;
      }
    __syncthreads();
#pragma unroll
    for (int mi = 0; mi < 4; ++mi)
#pragma unroll
      for (int j = 0; j < 4; ++j) {
        const int r = wr*64 + mi*16 + cr + j;
        const float mr = fmaxf(rmW[0][r], rmW[1][r]);
        u16* up = U + (size_t)(rowBase + r) * NM + wc*128 + cc;
#pragma unroll
        for (int ni = 0; ni < 8; ++ni) {
          const float phi = expf(SCALE_A * (acc[mi][ni][j] - mr)) * PHI_SCALE + EPSF;
          up[ni*16] = (u16)f2bf1(phi);
        }
      }
  } else {
    float lmax = -1e30f;
#pragma unroll
    for (int mi = 0; mi < 4; ++mi)
#pragma unroll
      for (int j = 0; j < 4; ++j) {
        const int r = wr*64 + mi*16 + cr + j;
        const float sq = sqv[rowBase + r];
#pragma unroll
        for (int ni = 0; ni < 8; ++ni) {
          const float z = SCALE_A * acc[mi][ni][j] - sq;
          acc[mi][ni][j] = z;
          lmax = fmaxf(lmax, z);
        }
      }
    lmax = fmaxf(lmax, __shfl_xor(lmax, 1));
    lmax = fmaxf(lmax, __shfl_xor(lmax, 2));
    lmax = fmaxf(lmax, __shfl_xor(lmax, 4));
    lmax = fmaxf(lmax, __shfl_xor(lmax, 8));
    lmax = fmaxf(lmax, __shfl_xor(lmax, 16));
    lmax = fmaxf(lmax, __shfl_xor(lmax, 32));
    if (lane == 0) wmax[wid] = lmax;
    __syncthreads();
    if (t == 0) {
      const float bm = fmaxf(fmaxf(wmax[0], wmax[1]), fmaxf(wmax[2], wmax[3]));
      atomicMax(gmax, f2key(bm));
    }
#pragma unroll
    for (int mi = 0; mi < 4; ++mi)
#pragma unroll
      for (int j = 0; j < 4; ++j) {
        const int r = wr*64 + mi*16 + cr + j;
        u16* up = U + (size_t)(rowBase + r) * NM + wc*128 + cc;
#pragma unroll
        for (int ni = 0; ni < 8; ++ni)
          up[ni*16] = (u16)f2bf1(expf(acc[mi][ni][j]));
      }
  }
}

__global__ void init_gmax(unsigned* g) { *g = 0u; }

__global__ void feat_k_b(u16* __restrict__ u, const unsigned* __restrict__ gmax)
{
  const size_t idx = (size_t)blockIdx.x * blockDim.x + threadIdx.x;
  const float eg = expf(-key2f(*gmax));
  const float e = bfh(u[idx]);
  u[idx] = (u16)f2bf1(e * eg * PHI_SCALE + EPSF);
}

// ---------------------------------------------------------------------------
// V transpose: qkv v-part (cols 3072..4095) -> vT[b][kh][d][s]
// ---------------------------------------------------------------------------
__global__ __launch_bounds__(256) void vtrans(const u16* __restrict__ v,
                                              u16* __restrict__ vT)
{
  const int s0 = blockIdx.x * 64;
  const int d0 = blockIdx.y * 64;
  const int bkv = blockIdx.z;
  const int b = bkv >> 3, kh = bkv & 7;
  const int t = threadIdx.x;
  __shared__ u16 Tt[64][80];
  const int sl = t >> 3;          // 0..31
  const int ds = (t & 7) * 8;
#pragma unroll
  for (int r = 0; r < 2; ++r) {
    const u16* src = v + (size_t)(b*NS + s0 + r*32 + sl) * 4096 + 3072 + kh*128 + d0 + ds;
    *(uint4*)&Tt[r*32 + sl][ds] = *(const uint4*)src;
  }
  __syncthreads();
#pragma unroll
  for (int r = 0; r < 2; ++r) {
    const int dl = r*32 + sl;
    u16 tmp[8];
#pragma unroll
    for (int j = 0; j < 8; ++j) tmp[j] = Tt[ds + j][dl];
    u16* dst = vT + (((size_t)(b*NKV + kh) * ND) + d0 + dl) * NS + s0 + ds;
    *(uint4*)dst = *(uint4*)tmp;
  }
}

// ---------------------------------------------------------------------------
// Per-chunk k-sums (raw, prefix applied later by prefix_ks).
// ---------------------------------------------------------------------------
__global__ __launch_bounds__(256) void ksum_chunk(const u16* __restrict__ phik,
                                                  float* __restrict__ ksst)
{
  const int c = blockIdx.x, bkv = blockIdx.y;
  const int b = bkv >> 3, kh = bkv & 7;
  const int m = threadIdx.x;
  const size_t base = ((size_t)(b*NS + c*128) * NKV + kh) * NM + m;
  float s = 0.f;
  for (int i = 0; i < 128; ++i) s += bfh(phik[base + (size_t)i * (NKV*NM)]);
  ksst[((size_t)bkv * NCNK + c) * NM + m] = s;
}

// ---------------------------------------------------------------------------
// MFMA per-chunk KV state: kvT[bkv][c][d][m] = sum_i vT[d, c*128+i]*phik[i, m].
// ---------------------------------------------------------------------------
__global__ __launch_bounds__(256) void chunk_kv_mfma(
    const u16* __restrict__ phik, const u16* __restrict__ vT,
    u16* __restrict__ kvT)
{
  const int c = blockIdx.x, bkv = blockIdx.y;
  const int b = bkv >> 3, kh = bkv & 7;
  const int t = threadIdx.x;
  const int lane = t & 63, wid = t >> 6;
  const int wr = wid >> 1, wc = wid & 1;
  const int fr = lane & 15, fk = (lane >> 4) * 8;
  const int cr = (lane >> 4) * 4, cc = lane & 15;
  const int sr = t >> 2, sk = (t & 3) * 8, e0 = t * 8;

  __shared__ u16 As[4096];      // [128 d][32 i]
  __shared__ u16 Bs[8192];      // [256 m][32 i], 16B-block swizzled

  const size_t vt_off = ((size_t)(b*NKV + kh) * ND) * NS + (size_t)c * 128;
  const size_t pk_row0 = ((size_t)(b*NS + c*128) * NKV + kh) * NM;
  const size_t pk_rstr = (size_t)NKV * NM;

  f32x4 acc[4][8];
#pragma unroll
  for (int i = 0; i < 4; ++i)
#pragma unroll
    for (int j = 0; j < 8; ++j) acc[i][j] = (f32x4){0.f, 0.f, 0.f, 0.f};

  const int m = t;
  const int sw = (m >> 1) & 3;

  for (int i0 = 0; i0 < 128; i0 += 32) {
    __syncthreads();   // previous step's fragments consumed
    GLL(vT + vt_off + (size_t)sr * NS + i0 + sk,        As + e0);
    GLL(vT + vt_off + (size_t)(sr + 64) * NS + i0 + sk, As + 2048 + e0);
    u16 rowv[32];
#pragma unroll
    for (int j = 0; j < 32; ++j)
      rowv[j] = phik[pk_row0 + (size_t)(i0 + j) * pk_rstr + m];
    u16* brow = Bs + m * 32;
#pragma unroll
    for (int q = 0; q < 4; ++q)
      *(uint4*)(brow + ((q ^ sw) * 8)) = *(const uint4*)(rowv + q*8);
    asm volatile("s_waitcnt vmcnt(0)" ::: "memory");
    __syncthreads();
    short8 a[4], bb[8];
#pragma unroll
    for (int mi = 0; mi < 4; ++mi)
      a[mi] = *(const short8*)(As + (wr*64 + mi*16 + fr)*32 + fk);
#pragma unroll
    for (int ni = 0; ni < 8; ++ni) {
      const int mrow = wc*128 + ni*16 + fr;
      const int q = fk >> 3;
      bb[ni] = *(const short8*)(Bs + mrow*32 + ((q ^ ((mrow >> 1) & 3)) << 3));
    }
#pragma unroll
    for (int mi = 0; mi < 4; ++mi)
#pragma unroll
      for (int ni = 0; ni < 8; ++ni)
        acc[mi][ni] = __builtin_amdgcn_mfma_f32_16x16x32_bf16(
            a[mi], bb[ni], acc[mi][ni], 0, 0, 0);
  }

  const size_t kv_off = ((size_t)bkv * NCNK + c) * (size_t)(ND*NM);
#pragma unroll
  for (int mi = 0; mi < 4; ++mi)
#pragma unroll
    for (int j = 0; j < 4; ++j) {
      const int d = wr*64 + mi*16 + cr + j;
#pragma unroll
      for (int ni = 0; ni < 8; ++ni) {
        const int mm = wc*128 + ni*16 + cc;
        kvT[kv_off + (size_t)d * NM + mm] = (u16)f2bf1(acc[mi][ni][j]);
      }
    }
}

// Exclusive prefix over the 32 chunks (elementwise walk, bf16 storage).
__global__ void prefix_kv(u16* __restrict__ kvst)
{
  const int md = blockIdx.x * 256 + threadIdx.x;        // 0..32767
  const size_t base = (size_t)blockIdx.y * NCNK * (NM*ND) + md;
  float carry = 0.f;
  for (int c = 0; c < NCNK; ++c) {
    const size_t a = base + (size_t)c * (NM*ND);
    const float val = bfh(kvst[a]);
    kvst[a] = (u16)f2bf1(carry);
    carry += val;
  }
}

__global__ void prefix_ks(float* __restrict__ ksst)
{
  const int m = threadIdx.x;
  const size_t base = (size_t)blockIdx.x * NCNK * NM + m;
  float carry = 0.f;
  for (int c = 0; c < NCNK; ++c) {
    const size_t a = base + (size_t)c * NM;
    const float val = ksst[a];
    ksst[a] = carry;
    carry += val;
  }
}

// ---------------------------------------------------------------------------
// MFMA per-chunk causal linear attention.
// ---------------------------------------------------------------------------
__global__ __launch_bounds__(256) void attn_mfma(
    const u16* __restrict__ phiq, const u16* __restrict__ phik,
    const u16* __restrict__ vT, const u16* __restrict__ kvT,
    const float* __restrict__ kspre, u16* __restrict__ attn)
{
  const int c = blockIdx.x, h = blockIdx.y, b = blockIdx.z;
  const int kh = h >> 1;                 // groups = 2
  const int bkv = b * NKV + kh;
  const int t = threadIdx.x;
  const int lane = t & 63, wid = t >> 6;
  const int wr = wid >> 1, wc = wid & 1;
  const int fr = lane & 15, fk = (lane >> 4) * 8;
  const int cr = (lane >> 4) * 4, cc = lane & 15;
  const int sr = t >> 2, sk = (t & 3) * 8, e0 = t * 8;

  __shared__ u16 As[4096];      // [128][32]
  __shared__ u16 Bs[4096];      // [128][32]
  __shared__ u16 Sl[16384];     // [128][128] swizzled bf16
  __shared__ float den_l[128];
  __shared__ float ks_l[256];

  const size_t pq_off = ((size_t)(b*NS + c*128) * NH  + h)  * NM;
  const size_t pk_off = ((size_t)(b*NS + c*128) * NKV + kh) * NM;
  const size_t vt_off = ((size_t)(b*NKV + kh) * ND) * (size_t)NS + (size_t)c * 128;
  const size_t kv_off = ((size_t)bkv * NCNK + c) * (size_t)(ND*NM);

  if (t < 128) den_l[t] = 0.f;
  ks_l[t] = kspre[((size_t)bkv * NCNK + c) * NM + t];

  const u16* Arp = As + (wr*64 + fr)*32 + fk;
  const u16* Brp = Bs + (wc*64 + fr)*32 + fk;

  // ---- phase A: S = Pq @ Pk^T -------------------------------------------
  f32x4 accS[4][4];
#pragma unroll
  for (int i = 0; i < 4; ++i)
#pragma unroll
    for (int j = 0; j < 4; ++j) accS[i][j] = (f32x4){0.f, 0.f, 0.f, 0.f};

  for (int k0 = 0; k0 < NM; k0 += 32) {
    GLL(phiq + pq_off + (size_t)sr * 4096 + k0 + sk,        As + e0);
    GLL(phiq + pq_off + (size_t)(sr + 64) * 4096 + k0 + sk, As + 2048 + e0);
    GLL(phik + pk_off + (size_t)sr * 2048 + k0 + sk,        Bs + e0);
    GLL(phik + pk_off + (size_t)(sr + 64) * 2048 + k0 + sk, Bs + 2048 + e0);
    asm volatile("s_waitcnt vmcnt(0)" ::: "memory");
    __syncthreads();
    short8 a[4], bb[4];
#pragma unroll
    for (int mi = 0; mi < 4; ++mi) a[mi] = *(const short8*)(Arp + mi*512);
#pragma unroll
    for (int ni = 0; ni < 4; ++ni) bb[ni] = *(const short8*)(Brp + ni*512);
#pragma unroll
    for (int mi = 0; mi < 4; ++mi)
#pragma unroll
      for (int ni = 0; ni < 4; ++ni)
        accS[mi][ni] = __builtin_amdgcn_mfma_f32_16x16x32_bf16(
            a[mi], bb[ni], accS[mi][ni], 0, 0, 0);
    __syncthreads();
  }

  // ---- mask + rowsum + write S to swizzled LDS ---------------------------
#pragma unroll
  for (int mi = 0; mi < 4; ++mi)
#pragma unroll
    for (int j = 0; j < 4; ++j) {
      const int r = wr*64 + mi*16 + cr + j;
      float s = 0.f;
#pragma unroll
      for (int ni = 0; ni < 4; ++ni) {
        const int cl = wc*64 + ni*16 + cc;
        float vv = accS[mi][ni][j];
        vv = (cl > r) ? 0.f : vv;
        accS[mi][ni][j] = vv;
        s += vv;
      }
      s += __shfl_xor(s, 1); s += __shfl_xor(s, 2);
      s += __shfl_xor(s, 4); s += __shfl_xor(s, 8);
      if (cc == 0) atomicAdd(&den_l[r], s);
#pragma unroll
      for (int ni = 0; ni < 4; ++ni) {
        const int cl = wc*64 + ni*16 + cc;
        u32 bo = ((u32)r << 8) + ((u32)cl << 1);
        bo ^= (u32)(r & 7) << 4;
        *(u16*)((char*)Sl + bo) = (u16)f2bf1(accS[mi][ni][j]);
      }
    }
  __syncthreads();

  // ---- phase C: acc2 = S @ V  (B-rows = vT[d][s]) ------------------------
  f32x4 acc2[4][4];
#pragma unroll
  for (int i = 0; i < 4; ++i)
#pragma unroll
    for (int j = 0; j < 4; ++j) acc2[i][j] = (f32x4){0.f, 0.f, 0.f, 0.f};

  for (int j0 = 0; j0 < 128; j0 += 32) {
    GLL(vT + vt_off + (size_t)sr * NS + j0 + sk,        Bs + e0);
    GLL(vT + vt_off + (size_t)(sr + 64) * NS + j0 + sk, Bs + 2048 + e0);
    asm volatile("s_waitcnt vmcnt(0)" ::: "memory");
    __syncthreads();
    short8 a[4], bb[4];
#pragma unroll
    for (int mi = 0; mi < 4; ++mi) {
      u32 bo = ((u32)(wr*64 + mi*16 + fr) << 8) + ((u32)(j0 + fk) << 1);
      bo ^= (u32)(fr & 7) << 4;
      a[mi] = *(const short8*)((const char*)Sl + bo);
    }
#pragma unroll
    for (int ni = 0; ni < 4; ++ni) bb[ni] = *(const short8*)(Brp + ni*512);
#pragma unroll
    for (int mi = 0; mi < 4; ++mi)
#pragma unroll
      for (int ni = 0; ni < 4; ++ni)
        acc2[mi][ni] = __builtin_amdgcn_mfma_f32_16x16x32_bf16(
            a[mi], bb[ni], acc2[mi][ni], 0, 0, 0);
    __syncthreads();
  }

  // ---- phase D: acc2 += Pq @ KVpre ; den += Pq . ks_prefix ---------------
  for (int m0 = 0; m0 < NM; m0 += 32) {
    GLL(phiq + pq_off + (size_t)sr * 4096 + m0 + sk,        As + e0);
    GLL(phiq + pq_off + (size_t)(sr + 64) * 4096 + m0 + sk, As + 2048 + e0);
    GLL(kvT + kv_off + (size_t)sr * NM + m0 + sk,           Bs + e0);
    GLL(kvT + kv_off + (size_t)(sr + 64) * NM + m0 + sk,    Bs + 2048 + e0);
    asm volatile("s_waitcnt vmcnt(0)" ::: "memory");
    __syncthreads();
    short8 a[4], bb[4];
#pragma unroll
    for (int mi = 0; mi < 4; ++mi) a[mi] = *(const short8*)(Arp + mi*512);
#pragma unroll
    for (int ni = 0; ni < 4; ++ni) bb[ni] = *(const short8*)(Brp + ni*512);
#pragma unroll
    for (int mi = 0; mi < 4; ++mi)
#pragma unroll
      for (int ni = 0; ni < 4; ++ni)
        acc2[mi][ni] = __builtin_amdgcn_mfma_f32_16x16x32_bf16(
            a[mi], bb[ni], acc2[mi][ni], 0, 0, 0);
    {
      const int pr = t >> 1;
      const int pm = (t & 1) * 16;
      float xf[16];
      unp8(*(const uint4*)(As + pr*32 + pm), xf);
      unp8(*(const uint4*)(As + pr*32 + pm + 8), xf + 8);
      float s = 0.f;
#pragma unroll
      for (int jj = 0; jj < 16; ++jj) s += xf[jj] * ks_l[m0 + pm + jj];
      s += __shfl_xor(s, 1);
      if (!(t & 1)) atomicAdd(&den_l[pr], s);
    }
    __syncthreads();
  }

  // ---- epilogue: out = acc2 / (den + eps) --------------------------------
#pragma unroll
  for (int mi = 0; mi < 4; ++mi)
#pragma unroll
    for (int j = 0; j < 4; ++j) {
      const int r = wr*64 + mi*16 + cr + j;
      const float inv = 1.0f / (den_l[r] + EPSF);
      u16* op = attn + ((size_t)(b*NS + c*128 + r) * NH + h) * ND + wc*64 + cc;
#pragma unroll
      for (int ni = 0; ni < 4; ++ni)
        op[ni*16] = (u16)f2bf1(acc2[mi][ni][j] * inv);
    }
}

// ---------------------------------------------------------------------------
extern "C" void kernel_launch(void* const* d_in, const int* in_sizes, int n_in,
                              void* d_out, int out_size, void* d_ws, size_t ws_size,
                              hipStream_t stream)
{
  const float* hidden = (const float*)d_in[0];
  const float* cosb   = (const float*)d_in[1];
  const float* sinb   = (const float*)d_in[2];
  const float* wq     = (const float*)d_in[3];
  const float* wk     = (const float*)d_in[4];
  const float* wv     = (const float*)d_in[5];
  const float* wo     = (const float*)d_in[6];
  const float* proj   = (const float*)d_in[7];
  float* out = (float*)d_out;

  const size_t MiB = 1024ull * 1024ull;
  if (ws_size < 186ull * MiB) {        // need ~185 MiB; certified >=192 MiB
    fill_out_f32<<<65536, 256, 0, stream>>>(out, 400.f);
    return;
  }

  // workspace (~185 MiB)
  u16* qkv  = (u16*)d_ws;                 // 33554432 bf16 [8192][4096]
  u16* phiq = qkv  + 33554432;            // 33554432 bf16
  u16* kvst = phiq + 33554432;            // 16777216 bf16 (KV^T chunk states)
  float* ksst = (float*)(kvst + 16777216);//   131072 f32
  unsigned* gmax = (unsigned*)(ksst + 131072);
  float* sqv = (float*)(gmax + 64);       //    65536 f32
  u16* wqkvb = (u16*)(sqv + 65536);       //  8388608 bf16 [4096][2048]
  u16* wob  = wqkvb + 8388608;            //  4194304 bf16
  u16* pb   = wob + 4194304;              //    65536 bf16 (P hi | P lo)
  u16* hb   = kvst;                       // hidden bf16 alias; dead before chunk
  u16* phik = (u16*)d_out;                // 32 MiB of d_out
  u16* vTb  = phik + 16777216;            // upper 32 MiB of d_out
  u16* attn = qkv;                        // attn overwrites qkv (dead by then)

  // 0) fp32 -> bf16 casts
  f2b<<<8192, 256, 0, stream>>>(hidden, hb);
  f2b<<<2048, 256, 0, stream>>>(wq, wqkvb);
  f2b<<<1024, 256, 0, stream>>>(wk, wqkvb + 2048*2048);
  f2b<<<1024, 256, 0, stream>>>(wv, wqkvb + 3072*2048);
  f2b<<<2048, 256, 0, stream>>>(wo, wob);
  f2b_split<<<128, 256, 0, stream>>>(proj, pb, pb + 32768);

  // 1) fused qkv projection: [8192][4096] = hb @ wqkvb^T  (256^2 8-phase)
  gemm_bt_256<u16><<<dim3(16, 32), 512, 0, stream>>>(hb, wqkvb, qkv, 2048, 4096);

  // 2) V transpose (v needs no RoPE), then RoPE on q,k in place
  vtrans<<<dim3(64, 2, 16), 256, 0, stream>>>(qkv, vTb);
  rope_bf<<<32768, 256, 0, stream>>>(qkv, cosb, sinb, NH, 0);
  rope_bf<<<16384, 256, 0, stream>>>(qkv, cosb, sinb, NKV, 2048);

  // 3) feature maps (MFMA, single-pass hi+lo)
  init_gmax<<<1, 1, 0, stream>>>(gmax);
  sqsum_k<<<256, 256, 0, stream>>>(qkv, sqv);
  feat_mfma<true , 4, 0   ><<<1024, 256, 0, stream>>>(qkv, pb, phiq, sqv, gmax);
  feat_mfma<false, 3, 2048><<< 512, 256, 0, stream>>>(qkv, pb, phik, sqv, gmax);
  feat_k_b<<<65536, 256, 0, stream>>>(phik, gmax);

  // 4) chunk states (MFMA, KV^T layout) + k-sums + exclusive prefixes
  chunk_kv_mfma<<<dim3(NCNK, NB*NKV), 256, 0, stream>>>(phik, vTb, kvst);
  ksum_chunk<<<dim3(NCNK, NB*NKV), 256, 0, stream>>>(phik, ksst);
  prefix_kv<<<dim3(128, NB*NKV), 256, 0, stream>>>(kvst);
  prefix_ks<<<NB*NKV, 256, 0, stream>>>(ksst);

  // 5) per-chunk causal linear attention (MFMA); writes attn into qkv region
  attn_mfma<<<dim3(NCNK, NH, NB), 256, 0, stream>>>(phiq, phik, vTb, kvst, ksst, attn);

  // 6) output projection (256^2 8-phase, fp32 out)
  gemm_bt_256<float><<<dim3(8, 32), 512, 0, stream>>>(attn, wob, out, 2048, 2048);
}